// Round 1
// baseline (4463.824 us; speedup 1.0000x reference)
//
#include <hip/hip_runtime.h>
#include <hip/hip_bf16.h>
#include <math.h>

#define NN 50000
#define EE 800000
#define DIN 128
#define HH 256
#define CC 47

// ---------------------------------------------------------------- degree
__global__ __launch_bounds__(256) void deg_kernel(const int* __restrict__ row,
                                                  float* __restrict__ deg) {
    int t = blockIdx.x * 256 + threadIdx.x;
    if (t < EE) atomicAdd(&deg[row[t]], 1.0f);
}

__global__ __launch_bounds__(256) void inv_kernel(const float* __restrict__ deg,
                                                  float* __restrict__ inv) {
    int t = blockIdx.x * 256 + threadIdx.x;
    if (t < NN) inv[t] = 1.0f / fmaxf(deg[t], 1.0f);
}

// ------------------------------------------------- scatter-add aggregation
// layer 1: feature dim 128. thread = (edge, 4-feature chunk)
__global__ __launch_bounds__(256) void scatter1(const float* __restrict__ x,
                                                const int* __restrict__ row,
                                                const int* __restrict__ col,
                                                float* __restrict__ a) {
    int t = blockIdx.x * 256 + threadIdx.x;
    int e = t >> 5;
    if (e >= EE) return;
    int c = (t & 31) << 2;
    int d = row[e], s = col[e];
    float4 v = *(const float4*)&x[(size_t)s * DIN + c];
    float* p = &a[(size_t)d * DIN + c];
    atomicAdd(p + 0, v.x); atomicAdd(p + 1, v.y);
    atomicAdd(p + 2, v.z); atomicAdd(p + 3, v.w);
}

// layer 2: feature dim 256
__global__ __launch_bounds__(256) void scatter2(const float* __restrict__ h1,
                                                const int* __restrict__ row,
                                                const int* __restrict__ col,
                                                float* __restrict__ a2) {
    int t = blockIdx.x * 256 + threadIdx.x;
    int e = t >> 6;
    if (e >= EE) return;
    int c = (t & 63) << 2;
    int d = row[e], s = col[e];
    float4 v = *(const float4*)&h1[(size_t)s * HH + c];
    float* p = &a2[(size_t)d * HH + c];
    atomicAdd(p + 0, v.x); atomicAdd(p + 1, v.y);
    atomicAdd(p + 2, v.z); atomicAdd(p + 3, v.w);
}

// ------------------------------------------------------------ layer-1 GEMM
// h1[i][j] = relu( inv_deg[i]*a[i][:] @ w1n[:,j] + x[i][:] @ w1s[:,j] + b1n[j]+b1s[j] )
__global__ __launch_bounds__(256) void gemm1_kernel(
    const float* __restrict__ a, const float* __restrict__ x,
    const float* __restrict__ inv_deg,
    const float* __restrict__ w1n, const float* __restrict__ b1n,
    const float* __restrict__ w1s, const float* __restrict__ b1s,
    float* __restrict__ h1)
{
    __shared__ float As[64][33];
    __shared__ float Ws[32][65];
    const int bi = blockIdx.x * 64;
    const int bj = blockIdx.y * 64;
    const int tid = threadIdx.x;
    const int tx = tid & 15, ty = tid >> 4;
    float acc[4][4] = {};

    for (int mat = 0; mat < 2; ++mat) {
        const float* __restrict__ A = mat ? x : a;
        const float* __restrict__ W = mat ? w1s : w1n;
        for (int k0 = 0; k0 < DIN; k0 += 32) {
            // A tile: 64 rows x 32 cols
#pragma unroll
            for (int l = 0; l < 2; ++l) {
                int f4 = tid + l * 256;          // 0..511
                int r = f4 >> 3;                 // 0..63
                int c4 = (f4 & 7) << 2;          // 0..28
                int gi = bi + r;
                float4 v = make_float4(0.f, 0.f, 0.f, 0.f);
                if (gi < NN) {
                    v = *(const float4*)&A[(size_t)gi * DIN + k0 + c4];
                    if (mat == 0) {
                        float s = inv_deg[gi];
                        v.x *= s; v.y *= s; v.z *= s; v.w *= s;
                    }
                }
                As[r][c4 + 0] = v.x; As[r][c4 + 1] = v.y;
                As[r][c4 + 2] = v.z; As[r][c4 + 3] = v.w;
            }
            // W tile: 32 rows x 64 cols
#pragma unroll
            for (int l = 0; l < 2; ++l) {
                int f4 = tid + l * 256;
                int r = f4 >> 4;                 // 0..31
                int c4 = (f4 & 15) << 2;         // 0..60
                float4 v = *(const float4*)&W[(size_t)(k0 + r) * HH + bj + c4];
                Ws[r][c4 + 0] = v.x; Ws[r][c4 + 1] = v.y;
                Ws[r][c4 + 2] = v.z; Ws[r][c4 + 3] = v.w;
            }
            __syncthreads();
#pragma unroll
            for (int kk = 0; kk < 32; ++kk) {
                float av[4], wv[4];
#pragma unroll
                for (int r = 0; r < 4; ++r) av[r] = As[ty * 4 + r][kk];
#pragma unroll
                for (int cix = 0; cix < 4; ++cix) wv[cix] = Ws[kk][tx * 4 + cix];
#pragma unroll
                for (int r = 0; r < 4; ++r)
#pragma unroll
                    for (int cix = 0; cix < 4; ++cix)
                        acc[r][cix] += av[r] * wv[cix];
            }
            __syncthreads();
        }
    }
#pragma unroll
    for (int r = 0; r < 4; ++r) {
        int gi = bi + ty * 4 + r;
        if (gi < NN) {
            int j0 = bj + tx * 4;
            float4 o;
            o.x = fmaxf(acc[r][0] + b1n[j0 + 0] + b1s[j0 + 0], 0.f);
            o.y = fmaxf(acc[r][1] + b1n[j0 + 1] + b1s[j0 + 1], 0.f);
            o.z = fmaxf(acc[r][2] + b1n[j0 + 2] + b1s[j0 + 2], 0.f);
            o.w = fmaxf(acc[r][3] + b1n[j0 + 3] + b1s[j0 + 3], 0.f);
            *(float4*)&h1[(size_t)gi * HH + j0] = o;
        }
    }
}

// --------------------------------------- layer-2 GEMM + log_softmax + loss
// block = 4 waves; each wave handles 4 nodes; lane j < 47 owns class j.
__global__ __launch_bounds__(256) void gemm2_loss_kernel(
    const float* __restrict__ a2, const float* __restrict__ h1,
    const float* __restrict__ inv_deg,
    const float* __restrict__ w2n, const float* __restrict__ b2n,
    const float* __restrict__ w2s, const float* __restrict__ b2s,
    const int* __restrict__ y, const int* __restrict__ mask,
    float* __restrict__ accum)
{
    __shared__ float sa[16][HH];
    __shared__ float sh[16][HH];
    __shared__ float red[8];
    const int i0 = blockIdx.x * 16;
    const int tid = threadIdx.x;

    // stage 16 nodes' a2 (scaled) and h1 rows into LDS
#pragma unroll
    for (int l = 0; l < 4; ++l) {
        int f4 = tid + l * 256;          // 0..1023
        int r = f4 >> 6;                 // node 0..15
        int c4 = (f4 & 63) << 2;         // 0..252
        int gi = i0 + r;
        float4 va = make_float4(0.f, 0.f, 0.f, 0.f), vh = va;
        if (gi < NN) {
            va = *(const float4*)&a2[(size_t)gi * HH + c4];
            float s = inv_deg[gi];
            va.x *= s; va.y *= s; va.z *= s; va.w *= s;
            vh = *(const float4*)&h1[(size_t)gi * HH + c4];
        }
        *(float4*)&sa[r][c4] = va;
        *(float4*)&sh[r][c4] = vh;
    }
    __syncthreads();

    const int wave = tid >> 6, lane = tid & 63;
    const int r0 = wave * 4;
    float bias = (lane < CC) ? (b2n[lane] + b2s[lane]) : 0.f;
    float acc[4];
    acc[0] = acc[1] = acc[2] = acc[3] = bias;

    if (lane < CC) {
        for (int k = 0; k < HH; ++k) {
            float wn = w2n[k * CC + lane];
            float wsd = w2s[k * CC + lane];
            acc[0] += sa[r0 + 0][k] * wn + sh[r0 + 0][k] * wsd;
            acc[1] += sa[r0 + 1][k] * wn + sh[r0 + 1][k] * wsd;
            acc[2] += sa[r0 + 2][k] * wn + sh[r0 + 2][k] * wsd;
            acc[3] += sa[r0 + 3][k] * wn + sh[r0 + 3][k] * wsd;
        }
    }

    float num = 0.f, den = 0.f;
#pragma unroll
    for (int r = 0; r < 4; ++r) {
        int gi = i0 + r0 + r;
        float lg = (lane < CC) ? acc[r] : -1e30f;
        float mx = lg;
#pragma unroll
        for (int off = 32; off >= 1; off >>= 1)
            mx = fmaxf(mx, __shfl_xor(mx, off));
        float ex = (lane < CC) ? __expf(acc[r] - mx) : 0.f;
        float sm = ex;
#pragma unroll
        for (int off = 32; off >= 1; off >>= 1)
            sm += __shfl_xor(sm, off);
        float lse = mx + __logf(sm);
        if (gi < NN) {                  // wave-uniform branch
            int yi = y[gi];
            float ly = __shfl(acc[r], yi);
            if (mask[gi]) { num += lse - ly; den += 1.f; }
        }
    }
    if (lane == 0) { red[wave * 2] = num; red[wave * 2 + 1] = den; }
    __syncthreads();
    if (tid == 0) {
        float n = red[0] + red[2] + red[4] + red[6];
        float d = red[1] + red[3] + red[5] + red[7];
        atomicAdd(&accum[0], n);
        atomicAdd(&accum[1], d);
    }
}

__global__ void finalize_kernel(const float* __restrict__ accum, float* __restrict__ out) {
    out[0] = accum[0] / fmaxf(accum[1], 1.0f);
}

// ---------------------------------------------------------------- launch
extern "C" void kernel_launch(void* const* d_in, const int* in_sizes, int n_in,
                              void* d_out, int out_size, void* d_ws, size_t ws_size,
                              hipStream_t stream) {
    const float* x   = (const float*)d_in[0];
    const int*   row = (const int*)d_in[1];
    const int*   col = (const int*)d_in[2];
    const int*   y   = (const int*)d_in[3];
    const int*   msk = (const int*)d_in[4];
    const float* w1n = (const float*)d_in[5];
    const float* b1n = (const float*)d_in[6];
    const float* w1s = (const float*)d_in[7];
    const float* b1s = (const float*)d_in[8];
    const float* w2n = (const float*)d_in[9];
    const float* b2n = (const float*)d_in[10];
    const float* w2s = (const float*)d_in[11];
    const float* b2s = (const float*)d_in[12];
    float* out = (float*)d_out;

    // workspace layout (floats):
    //   accum[64] | deg[50048] | inv[50048] | h1[N*256] | buf[N*256]
    // buf serves as `a` (first N*128) for layer 1, then reused as `a2`.
    float* ws    = (float*)d_ws;
    float* accum = ws;
    float* deg   = ws + 64;
    float* inv   = deg + 50048;
    float* h1    = inv + 50048;
    float* buf   = h1 + (size_t)NN * HH;
    float* a     = buf;                 // N x 128
    float* a2    = buf;                 // N x 256 (after gemm1)

    hipMemsetAsync(accum, 0, (64 + 50048) * sizeof(float), stream);   // accum + deg
    hipMemsetAsync(a, 0, (size_t)NN * DIN * sizeof(float), stream);

    deg_kernel<<<(EE + 255) / 256, 256, 0, stream>>>(row, deg);
    inv_kernel<<<(NN + 255) / 256, 256, 0, stream>>>(deg, inv);
    scatter1<<<EE / 8, 256, 0, stream>>>(x, row, col, a);

    dim3 g1((NN + 63) / 64, HH / 64);
    gemm1_kernel<<<g1, 256, 0, stream>>>(a, x, inv, w1n, b1n, w1s, b1s, h1);

    hipMemsetAsync(a2, 0, (size_t)NN * HH * sizeof(float), stream);
    scatter2<<<EE / 4, 256, 0, stream>>>(h1, row, col, a2);

    gemm2_loss_kernel<<<(NN + 15) / 16, 256, 0, stream>>>(
        a2, h1, inv, w2n, b2n, w2s, b2s, y, msk, accum);

    finalize_kernel<<<1, 1, 0, stream>>>(accum, out);
}

// Round 2
// 802.198 us; speedup vs baseline: 5.5645x; 5.5645x over previous
//
#include <hip/hip_runtime.h>
#include <hip/hip_bf16.h>
#include <math.h>

#define NN 50000
#define EE 800000
#define DIN 128
#define HH 256
#define CC 47

// ---------------------------------------------------------------- degree
__global__ __launch_bounds__(256) void deg_kernel(const int* __restrict__ row,
                                                  int* __restrict__ deg) {
    int t = blockIdx.x * 256 + threadIdx.x;
    if (t < EE) atomicAdd(&deg[row[t]], 1);
}

// ------------------------------------------------------- exclusive scan (3k)
__global__ __launch_bounds__(256) void scan1(const int* __restrict__ deg,
                                             int* __restrict__ row_ptr,
                                             int* __restrict__ partial) {
    __shared__ int tot[4], pre[4];
    int tid = threadIdx.x, t = blockIdx.x * 256 + tid;
    int lane = tid & 63, wave = tid >> 6;
    int v = (t < NN) ? deg[t] : 0;
    int incl = v;
#pragma unroll
    for (int off = 1; off < 64; off <<= 1) {
        int u = __shfl_up(incl, off);
        if (lane >= off) incl += u;
    }
    if (lane == 63) tot[wave] = incl;
    __syncthreads();
    if (tid == 0) {
        int s = 0;
#pragma unroll
        for (int w = 0; w < 4; ++w) { pre[w] = s; s += tot[w]; }
        partial[blockIdx.x] = s;
    }
    __syncthreads();
    if (t < NN) row_ptr[t] = incl - v + pre[wave];
}

__global__ __launch_bounds__(256) void scan2(int* __restrict__ partial, int nblk) {
    __shared__ int tot[4], pre[4];
    int tid = threadIdx.x;
    int lane = tid & 63, wave = tid >> 6;
    int v = (tid < nblk) ? partial[tid] : 0;
    int incl = v;
#pragma unroll
    for (int off = 1; off < 64; off <<= 1) {
        int u = __shfl_up(incl, off);
        if (lane >= off) incl += u;
    }
    if (lane == 63) tot[wave] = incl;
    __syncthreads();
    if (tid == 0) {
        int s = 0;
#pragma unroll
        for (int w = 0; w < 4; ++w) { pre[w] = s; s += tot[w]; }
    }
    __syncthreads();
    partial[tid] = incl - v + pre[wave];
}

__global__ __launch_bounds__(256) void scan3(const int* __restrict__ deg,
                                             int* __restrict__ row_ptr,
                                             const int* __restrict__ partial,
                                             int* __restrict__ cursor,
                                             float* __restrict__ inv) {
    int t = blockIdx.x * 256 + threadIdx.x;
    if (t < NN) {
        int rp = row_ptr[t] + partial[blockIdx.x];
        row_ptr[t] = rp;
        cursor[t] = rp;
        inv[t] = 1.0f / fmaxf((float)deg[t], 1.0f);
    }
    if (t == 0) row_ptr[NN] = EE;
}

__global__ __launch_bounds__(256) void fill_kernel(const int* __restrict__ row,
                                                   const int* __restrict__ col,
                                                   int* __restrict__ cursor,
                                                   int* __restrict__ csr) {
    int e = blockIdx.x * 256 + threadIdx.x;
    if (e < EE) {
        int r = row[e];
        int pos = atomicAdd(&cursor[r], 1);
        csr[pos] = col[e];
    }
}

// ----------------------------------------------- layer-1 gather aggregation
// wave per node; lane owns 2 features (float2). a[i] = mean of x over nbrs.
__global__ __launch_bounds__(256) void agg1(const float* __restrict__ x,
                                            const int* __restrict__ rp,
                                            const int* __restrict__ csr,
                                            const float* __restrict__ inv,
                                            float* __restrict__ a) {
    int wave = threadIdx.x >> 6, lane = threadIdx.x & 63;
    int i = blockIdx.x * 4 + wave;
    if (i >= NN) return;
    int s = rp[i], e = rp[i + 1];
    float2 acc = make_float2(0.f, 0.f);
    const float* xx = x + lane * 2;
    for (int k = s; k < e; ++k) {
        int nbr = csr[k];
        float2 v = *(const float2*)&xx[(size_t)nbr * DIN];
        acc.x += v.x; acc.y += v.y;
    }
    float sc = inv[i];
    float2 o = make_float2(acc.x * sc, acc.y * sc);
    *(float2*)&a[(size_t)i * DIN + lane * 2] = o;
}

// ------------------------------------------------------------ layer-1 GEMM
// h1[i][j] = relu( a[i][:] @ w1n[:,j] + x[i][:] @ w1s[:,j] + b1n[j]+b1s[j] )
__global__ __launch_bounds__(256) void gemm1_kernel(
    const float* __restrict__ a, const float* __restrict__ x,
    const float* __restrict__ w1n, const float* __restrict__ b1n,
    const float* __restrict__ w1s, const float* __restrict__ b1s,
    float* __restrict__ h1)
{
    __shared__ float As[64][33];
    __shared__ float Ws[32][65];
    const int bi = blockIdx.x * 64;
    const int bj = blockIdx.y * 64;
    const int tid = threadIdx.x;
    const int tx = tid & 15, ty = tid >> 4;
    float acc[4][4] = {};

    for (int mat = 0; mat < 2; ++mat) {
        const float* __restrict__ A = mat ? x : a;
        const float* __restrict__ W = mat ? w1s : w1n;
        for (int k0 = 0; k0 < DIN; k0 += 32) {
#pragma unroll
            for (int l = 0; l < 2; ++l) {
                int f4 = tid + l * 256;
                int r = f4 >> 3;
                int c4 = (f4 & 7) << 2;
                int gi = bi + r;
                float4 v = make_float4(0.f, 0.f, 0.f, 0.f);
                if (gi < NN) v = *(const float4*)&A[(size_t)gi * DIN + k0 + c4];
                As[r][c4 + 0] = v.x; As[r][c4 + 1] = v.y;
                As[r][c4 + 2] = v.z; As[r][c4 + 3] = v.w;
            }
#pragma unroll
            for (int l = 0; l < 2; ++l) {
                int f4 = tid + l * 256;
                int r = f4 >> 4;
                int c4 = (f4 & 15) << 2;
                float4 v = *(const float4*)&W[(size_t)(k0 + r) * HH + bj + c4];
                Ws[r][c4 + 0] = v.x; Ws[r][c4 + 1] = v.y;
                Ws[r][c4 + 2] = v.z; Ws[r][c4 + 3] = v.w;
            }
            __syncthreads();
#pragma unroll
            for (int kk = 0; kk < 32; ++kk) {
                float av[4], wv[4];
#pragma unroll
                for (int r = 0; r < 4; ++r) av[r] = As[ty * 4 + r][kk];
#pragma unroll
                for (int cix = 0; cix < 4; ++cix) wv[cix] = Ws[kk][tx * 4 + cix];
#pragma unroll
                for (int r = 0; r < 4; ++r)
#pragma unroll
                    for (int cix = 0; cix < 4; ++cix)
                        acc[r][cix] += av[r] * wv[cix];
            }
            __syncthreads();
        }
    }
#pragma unroll
    for (int r = 0; r < 4; ++r) {
        int gi = bi + ty * 4 + r;
        if (gi < NN) {
            int j0 = bj + tx * 4;
            float4 o;
            o.x = fmaxf(acc[r][0] + b1n[j0 + 0] + b1s[j0 + 0], 0.f);
            o.y = fmaxf(acc[r][1] + b1n[j0 + 1] + b1s[j0 + 1], 0.f);
            o.z = fmaxf(acc[r][2] + b1n[j0 + 2] + b1s[j0 + 2], 0.f);
            o.w = fmaxf(acc[r][3] + b1n[j0 + 3] + b1s[j0 + 3], 0.f);
            *(float4*)&h1[(size_t)gi * HH + j0] = o;
        }
    }
}

// ----------------------------------------------- layer-2 GEMM to 47-dim (x2)
// z[i][0:47]  = h1[i] @ w2n   (col 47 zero-padded)
// z[i][48:95] = h1[i] @ w2s
__global__ __launch_bounds__(256) void gemm2z_kernel(
    const float* __restrict__ h1,
    const float* __restrict__ w2n, const float* __restrict__ w2s,
    float* __restrict__ z)
{
    __shared__ float sh[16][HH];
    const int i0 = blockIdx.x * 16;
    const int tid = threadIdx.x;
#pragma unroll
    for (int l = 0; l < 4; ++l) {
        int idx = tid + l * 256;
        int r = idx >> 6;
        int c4 = (idx & 63) << 2;
        int gi = i0 + r;
        float4 v = make_float4(0.f, 0.f, 0.f, 0.f);
        if (gi < NN) v = *(const float4*)&h1[(size_t)gi * HH + c4];
        *(float4*)&sh[r][c4] = v;
    }
    __syncthreads();

    const int wave = tid >> 6, lane = tid & 63;
    const int r0 = wave * 4;
    if (lane >= 48) return;

    float an[4] = {}, as_[4] = {};
    if (lane < CC) {
        for (int k = 0; k < HH; ++k) {
            float wn = w2n[k * CC + lane];
            float wsv = w2s[k * CC + lane];
#pragma unroll
            for (int r = 0; r < 4; ++r) {
                float h = sh[r0 + r][k];
                an[r] += h * wn;
                as_[r] += h * wsv;
            }
        }
    }
#pragma unroll
    for (int r = 0; r < 4; ++r) {
        int gi = i0 + r0 + r;
        if (gi < NN) {
            z[(size_t)gi * 96 + lane]      = (lane < CC) ? an[r]  : 0.f;
            z[(size_t)gi * 96 + 48 + lane] = (lane < CC) ? as_[r] : 0.f;
        }
    }
}

// ----------------------- 47-dim gather-aggregate + log_softmax + NLL + mean
__global__ __launch_bounds__(256) void loss_kernel(
    const float* __restrict__ z,
    const int* __restrict__ rp, const int* __restrict__ csr,
    const float* __restrict__ inv,
    const float* __restrict__ b2n, const float* __restrict__ b2s,
    const int* __restrict__ y, const int* __restrict__ mask,
    float* __restrict__ accum)
{
    __shared__ float red[8];
    const int tid = threadIdx.x;
    const int wave = tid >> 6, lane = tid & 63;
    const int i = blockIdx.x * 4 + wave;
    float num = 0.f, den = 0.f;

    if (i < NN) {
        int s = rp[i], e = rp[i + 1];
        float agg = 0.f;
        for (int k = s; k < e; ++k) {
            int nbr = csr[k];
            agg += z[(size_t)nbr * 96 + lane];   // lanes >= 47 read zs region; masked below
        }
        float logit;
        if (lane < CC) {
            float zsv = z[(size_t)i * 96 + 48 + lane];
            logit = agg * inv[i] + zsv + b2n[lane] + b2s[lane];
        } else {
            logit = -1e30f;
        }
        float mx = logit;
#pragma unroll
        for (int off = 32; off >= 1; off >>= 1)
            mx = fmaxf(mx, __shfl_xor(mx, off));
        float ex = (lane < CC) ? __expf(logit - mx) : 0.f;
        float sm = ex;
#pragma unroll
        for (int off = 32; off >= 1; off >>= 1)
            sm += __shfl_xor(sm, off);
        float lse = mx + __logf(sm);
        int yi = y[i];
        float ly = __shfl(logit, yi);
        if (lane == 0 && mask[i]) { num = lse - ly; den = 1.f; }
    }
    if (lane == 0) { red[wave * 2] = num; red[wave * 2 + 1] = den; }
    __syncthreads();
    if (tid == 0) {
        atomicAdd(&accum[0], red[0] + red[2] + red[4] + red[6]);
        atomicAdd(&accum[1], red[1] + red[3] + red[5] + red[7]);
    }
}

__global__ void finalize_kernel(const float* __restrict__ accum, float* __restrict__ out) {
    out[0] = accum[0] / fmaxf(accum[1], 1.0f);
}

// ---------------------------------------------------------------- launch
extern "C" void kernel_launch(void* const* d_in, const int* in_sizes, int n_in,
                              void* d_out, int out_size, void* d_ws, size_t ws_size,
                              hipStream_t stream) {
    const float* x   = (const float*)d_in[0];
    const int*   row = (const int*)d_in[1];
    const int*   col = (const int*)d_in[2];
    const int*   y   = (const int*)d_in[3];
    const int*   msk = (const int*)d_in[4];
    const float* w1n = (const float*)d_in[5];
    const float* b1n = (const float*)d_in[6];
    const float* w1s = (const float*)d_in[7];
    const float* b1s = (const float*)d_in[8];
    const float* w2n = (const float*)d_in[9];
    const float* b2n = (const float*)d_in[10];
    const float* w2s = (const float*)d_in[11];
    const float* b2s = (const float*)d_in[12];
    float* out = (float*)d_out;

    // workspace layout:
    //   accum[64]f | deg[50048]i | row_ptr[50048]i | cursor[50048]i |
    //   partial[256]i | csr[800000]i | inv[50048]f | a[N*128]f |
    //   h1[N*256]f | z[N*96]f                      (~100 MB total)
    float* ws      = (float*)d_ws;
    float* accum   = ws;
    int*   deg     = (int*)(ws + 64);
    int*   row_ptr = deg + 50048;
    int*   cursor  = row_ptr + 50048;
    int*   partial = cursor + 50048;
    int*   csr     = partial + 256;
    float* inv     = (float*)(csr + 800000);
    float* a       = inv + 50048;
    float* h1      = a + (size_t)NN * DIN;
    float* z       = h1 + (size_t)NN * HH;

    const int NBLK = (NN + 255) / 256;   // 196

    hipMemsetAsync(accum, 0, (64 + 50048) * sizeof(float), stream);  // accum + deg

    deg_kernel<<<(EE + 255) / 256, 256, 0, stream>>>(row, deg);
    scan1<<<NBLK, 256, 0, stream>>>(deg, row_ptr, partial);
    scan2<<<1, 256, 0, stream>>>(partial, NBLK);
    scan3<<<NBLK, 256, 0, stream>>>(deg, row_ptr, partial, cursor, inv);
    fill_kernel<<<(EE + 255) / 256, 256, 0, stream>>>(row, col, cursor, csr);

    agg1<<<(NN + 3) / 4, 256, 0, stream>>>(x, row_ptr, csr, inv, a);

    dim3 g1((NN + 63) / 64, HH / 64);
    gemm1_kernel<<<g1, 256, 0, stream>>>(a, x, w1n, b1n, w1s, b1s, h1);

    gemm2z_kernel<<<(NN + 15) / 16, 256, 0, stream>>>(h1, w2n, w2s, z);

    loss_kernel<<<(NN + 3) / 4, 256, 0, stream>>>(
        z, row_ptr, csr, inv, b2n, b2s, y, msk, accum);

    finalize_kernel<<<1, 1, 0, stream>>>(accum, out);
}

// Round 5
// 615.503 us; speedup vs baseline: 7.2523x; 1.3033x over previous
//
#include <hip/hip_runtime.h>
#include <math.h>

#define NN 50000
#define EE 800000
#define DIN 128
#define HH 256
#define CC 47
#define LK2 264   // LDS row stride in bf16 (256 + 8 pad)

typedef short bf16x8 __attribute__((ext_vector_type(8)));
typedef float f32x4 __attribute__((ext_vector_type(4)));

static __device__ __forceinline__ unsigned short f2bf(float f) {
    unsigned u = __float_as_uint(f);
    u = u + 0x7fff + ((u >> 16) & 1);
    return (unsigned short)(u >> 16);
}
static __device__ __forceinline__ float bflo(unsigned u) { return __uint_as_float(u << 16); }
static __device__ __forceinline__ float bfhi(unsigned u) { return __uint_as_float(u & 0xffff0000u); }

// ---------------------------------------------------------------- degree
__global__ __launch_bounds__(256) void deg_kernel(const int* __restrict__ row,
                                                  int* __restrict__ deg) {
    int t = blockIdx.x * 256 + threadIdx.x;
    if (t < EE) atomicAdd(&deg[row[t]], 1);
}

// ------------------------------------------------------- exclusive scan (3k)
__global__ __launch_bounds__(256) void scan1(const int* __restrict__ deg,
                                             int* __restrict__ row_ptr,
                                             int* __restrict__ partial) {
    __shared__ int tot[4], pre[4];
    int tid = threadIdx.x, t = blockIdx.x * 256 + tid;
    int lane = tid & 63, wave = tid >> 6;
    int v = (t < NN) ? deg[t] : 0;
    int incl = v;
#pragma unroll
    for (int off = 1; off < 64; off <<= 1) {
        int u = __shfl_up(incl, off);
        if (lane >= off) incl += u;
    }
    if (lane == 63) tot[wave] = incl;
    __syncthreads();
    if (tid == 0) {
        int s = 0;
#pragma unroll
        for (int w = 0; w < 4; ++w) { pre[w] = s; s += tot[w]; }
        partial[blockIdx.x] = s;
    }
    __syncthreads();
    if (t < NN) row_ptr[t] = incl - v + pre[wave];
}

__global__ __launch_bounds__(256) void scan2(int* __restrict__ partial, int nblk) {
    __shared__ int tot[4], pre[4];
    int tid = threadIdx.x;
    int lane = tid & 63, wave = tid >> 6;
    int v = (tid < nblk) ? partial[tid] : 0;
    int incl = v;
#pragma unroll
    for (int off = 1; off < 64; off <<= 1) {
        int u = __shfl_up(incl, off);
        if (lane >= off) incl += u;
    }
    if (lane == 63) tot[wave] = incl;
    __syncthreads();
    if (tid == 0) {
        int s = 0;
#pragma unroll
        for (int w = 0; w < 4; ++w) { pre[w] = s; s += tot[w]; }
    }
    __syncthreads();
    partial[tid] = incl - v + pre[wave];
}

__global__ __launch_bounds__(256) void scan3(const int* __restrict__ deg,
                                             int* __restrict__ row_ptr,
                                             const int* __restrict__ partial,
                                             int* __restrict__ cursor,
                                             float* __restrict__ inv) {
    int t = blockIdx.x * 256 + threadIdx.x;
    if (t < NN) {
        int rp = row_ptr[t] + partial[blockIdx.x];
        row_ptr[t] = rp;
        cursor[t] = rp;
        inv[t] = 1.0f / fmaxf((float)deg[t], 1.0f);
    }
    if (t == 0) row_ptr[NN] = EE;
}

__global__ __launch_bounds__(256) void fill_kernel(const int* __restrict__ row,
                                                   const int* __restrict__ col,
                                                   int* __restrict__ cursor,
                                                   int* __restrict__ csr) {
    int e = blockIdx.x * 256 + threadIdx.x;
    if (e < EE) {
        int r = row[e];
        int pos = atomicAdd(&cursor[r], 1);
        csr[pos] = col[e];
    }
}

// ------------------------------------------------- x -> bf16 (xb and ab[:,128:])
__global__ __launch_bounds__(256) void convert_x(const float* __restrict__ x,
                                                 unsigned* __restrict__ xb,
                                                 unsigned* __restrict__ ab) {
    int t = blockIdx.x * 256 + threadIdx.x;      // one per bf16 pair
    if (t >= NN * 64) return;
    int i = t >> 6, l = t & 63;
    float2 v = *(const float2*)&x[(size_t)i * DIN + l * 2];
    unsigned p = (unsigned)f2bf(v.x) | ((unsigned)f2bf(v.y) << 16);
    xb[t] = p;
    ab[(size_t)i * 128 + 64 + l] = p;
}

// --------------------------------------------------- weight repack (bf16, [n][k])
__global__ __launch_bounds__(256) void repack_w(
    const float* __restrict__ w1n, const float* __restrict__ w1s,
    const float* __restrict__ b1n, const float* __restrict__ b1s,
    const float* __restrict__ w2n, const float* __restrict__ w2s,
    unsigned short* __restrict__ WB1, unsigned short* __restrict__ WB2,
    float* __restrict__ bias1)
{
    int t = blockIdx.x * 256 + threadIdx.x;
    if (t < 65536) {
        int n = t >> 8, k = t & 255;
        float v = (k < 128) ? w1n[k * HH + n] : w1s[(k - 128) * HH + n];
        WB1[n * 256 + k] = f2bf(v);
    } else if (t < 65536 + 24576) {
        int q = t - 65536;
        int n = q >> 8, k = q & 255;
        float v;
        if (n < 48) v = (n < CC) ? w2n[k * CC + n] : 0.f;
        else { int m = n - 48; v = (m < CC) ? w2s[k * CC + m] : 0.f; }
        WB2[n * 256 + k] = f2bf(v);
    } else if (t < 65536 + 24576 + 256) {
        int n = t - 65536 - 24576;
        bias1[n] = b1n[n] + b1s[n];
    }
}

// ----------------------------------------------- layer-1 gather aggregation
// wave per node; lane owns 2 bf16 features (one dword). 4x unrolled.
__global__ __launch_bounds__(256) void agg1(const unsigned* __restrict__ xb,
                                            const int* __restrict__ rp,
                                            const int* __restrict__ csr,
                                            const float* __restrict__ inv,
                                            unsigned* __restrict__ ab) {
    int wave = threadIdx.x >> 6, lane = threadIdx.x & 63;
    int i = blockIdx.x * 4 + wave;
    if (i >= NN) return;
    int s = rp[i], e = rp[i + 1];
    float x0 = 0, y0 = 0, x1 = 0, y1 = 0, x2 = 0, y2 = 0, x3 = 0, y3 = 0;
    int k = s, m4 = s + ((e - s) & ~3);
    for (; k < m4; k += 4) {
        int n0 = csr[k], n1 = csr[k + 1], n2 = csr[k + 2], n3 = csr[k + 3];
        unsigned u0 = xb[(size_t)n0 * 64 + lane];
        unsigned u1 = xb[(size_t)n1 * 64 + lane];
        unsigned u2 = xb[(size_t)n2 * 64 + lane];
        unsigned u3 = xb[(size_t)n3 * 64 + lane];
        x0 += bflo(u0); y0 += bfhi(u0);
        x1 += bflo(u1); y1 += bfhi(u1);
        x2 += bflo(u2); y2 += bfhi(u2);
        x3 += bflo(u3); y3 += bfhi(u3);
    }
    for (; k < e; ++k) {
        unsigned u = xb[(size_t)csr[k] * 64 + lane];
        x0 += bflo(u); y0 += bfhi(u);
    }
    float sc = inv[i];
    float ax = ((x0 + x1) + (x2 + x3)) * sc;
    float ay = ((y0 + y1) + (y2 + y3)) * sc;
    ab[(size_t)i * 128 + lane] = (unsigned)f2bf(ax) | ((unsigned)f2bf(ay) << 16);
}

// ------------------------------------------------------- layer-1 MFMA GEMM
// h1[i][n] = relu( AB[i][:] (1x256 bf16) . WB1[n][:] + bias1[n] ), bf16 out
__global__ __launch_bounds__(256) void gemm1_mfma(
    const unsigned short* __restrict__ AB, const unsigned short* __restrict__ WB1,
    const float* __restrict__ bias1, unsigned short* __restrict__ h1b)
{
    __shared__ unsigned short sA[64 * LK2];
    __shared__ unsigned short sB[64 * LK2];
    const int tid = threadIdx.x;
    const int i0 = blockIdx.x * 64;
    const int n0 = blockIdx.y * 64;
    const int wv = tid >> 6, lane = tid & 63;
    const int g = lane >> 4, l16 = lane & 15;
    const int m0 = (wv >> 1) * 32, q0 = (wv & 1) * 32;

    f32x4 acc00 = {}, acc01 = {}, acc10 = {}, acc11 = {};

    // stage full 64x256 A-tile and B-tile (2048 int4 chunks each)
#pragma unroll
    for (int l = 0; l < 8; ++l) {
        int c = tid + l * 256;              // 0..2047
        int r = c >> 5, c8 = (c & 31) * 8;  // row 0..63, col 0..248
        int gi = i0 + r;
        int4 v = make_int4(0, 0, 0, 0);
        if (gi < NN) v = *(const int4*)&AB[(size_t)gi * 256 + c8];
        *(int4*)&sA[r * LK2 + c8] = v;
        int4 w = *(const int4*)&WB1[(size_t)(n0 + r) * 256 + c8];
        *(int4*)&sB[r * LK2 + c8] = w;
    }
    __syncthreads();
#pragma unroll
    for (int kk = 0; kk < 256; kk += 32) {
        bf16x8 a0 = *(const bf16x8*)&sA[(m0 + l16) * LK2 + kk + g * 8];
        bf16x8 a1 = *(const bf16x8*)&sA[(m0 + 16 + l16) * LK2 + kk + g * 8];
        bf16x8 b0 = *(const bf16x8*)&sB[(q0 + l16) * LK2 + kk + g * 8];
        bf16x8 b1 = *(const bf16x8*)&sB[(q0 + 16 + l16) * LK2 + kk + g * 8];
        acc00 = __builtin_amdgcn_mfma_f32_16x16x32_bf16(a0, b0, acc00, 0, 0, 0);
        acc01 = __builtin_amdgcn_mfma_f32_16x16x32_bf16(a0, b1, acc01, 0, 0, 0);
        acc10 = __builtin_amdgcn_mfma_f32_16x16x32_bf16(a1, b0, acc10, 0, 0, 0);
        acc11 = __builtin_amdgcn_mfma_f32_16x16x32_bf16(a1, b1, acc11, 0, 0, 0);
    }
    int colA = n0 + q0 + l16;
    int colB = colA + 16;
    float bA = bias1[colA], bB = bias1[colB];
#pragma unroll
    for (int r = 0; r < 4; ++r) {
        int rowi = g * 4 + r;
        int giA = i0 + m0 + rowi;
        int giB = giA + 16;
        if (giA < NN) {
            h1b[(size_t)giA * 256 + colA] = f2bf(fmaxf(acc00[r] + bA, 0.f));
            h1b[(size_t)giA * 256 + colB] = f2bf(fmaxf(acc01[r] + bB, 0.f));
        }
        if (giB < NN) {
            h1b[(size_t)giB * 256 + colA] = f2bf(fmaxf(acc10[r] + bA, 0.f));
            h1b[(size_t)giB * 256 + colB] = f2bf(fmaxf(acc11[r] + bB, 0.f));
        }
    }
}

// ------------------------------------------------------- layer-2 MFMA GEMM
// z[i][n] = h1[i][:] . WB2[n][:]   (n in [0,96); cols 47,95 are zero weights)
__global__ __launch_bounds__(256) void gemm2_mfma(
    const unsigned short* __restrict__ h1b, const unsigned short* __restrict__ WB2,
    float* __restrict__ z)
{
    __shared__ unsigned short sA[64 * LK2];
    __shared__ unsigned short sB[48 * LK2];
    const int tid = threadIdx.x;
    const int i0 = blockIdx.x * 64;
    const int n0 = blockIdx.y * 48;
    const int wv = tid >> 6, lane = tid & 63;
    const int g = lane >> 4, l16 = lane & 15;
    const int m0 = wv * 16;
    f32x4 acc[3] = {};

#pragma unroll
    for (int l = 0; l < 8; ++l) {
        int c = tid + l * 256;              // 0..2047
        int r = c >> 5, c8 = (c & 31) * 8;
        int gi = i0 + r;
        int4 v = make_int4(0, 0, 0, 0);
        if (gi < NN) v = *(const int4*)&h1b[(size_t)gi * 256 + c8];
        *(int4*)&sA[r * LK2 + c8] = v;
    }
#pragma unroll
    for (int l = 0; l < 6; ++l) {
        int c = tid + l * 256;              // 0..1535
        int r = c >> 5, c8 = (c & 31) * 8;  // row 0..47
        *(int4*)&sB[r * LK2 + c8] = *(const int4*)&WB2[(size_t)(n0 + r) * 256 + c8];
    }
    __syncthreads();
#pragma unroll
    for (int kk = 0; kk < 256; kk += 32) {
        bf16x8 af = *(const bf16x8*)&sA[(m0 + l16) * LK2 + kk + g * 8];
#pragma unroll
        for (int ni = 0; ni < 3; ++ni) {
            bf16x8 bfv = *(const bf16x8*)&sB[(ni * 16 + l16) * LK2 + kk + g * 8];
            acc[ni] = __builtin_amdgcn_mfma_f32_16x16x32_bf16(af, bfv, acc[ni], 0, 0, 0);
        }
    }
#pragma unroll
    for (int ni = 0; ni < 3; ++ni) {
        int col = n0 + ni * 16 + l16;
#pragma unroll
        for (int r = 0; r < 4; ++r) {
            int gi = i0 + m0 + g * 4 + r;
            if (gi < NN) z[(size_t)gi * 96 + col] = acc[ni][r];
        }
    }
}

// ----------------------- 47-dim gather-aggregate + log_softmax + NLL + mean
__global__ __launch_bounds__(256) void loss_kernel(
    const float* __restrict__ z,
    const int* __restrict__ rp, const int* __restrict__ csr,
    const float* __restrict__ inv,
    const float* __restrict__ b2n, const float* __restrict__ b2s,
    const int* __restrict__ y, const int* __restrict__ mask,
    float* __restrict__ accum)
{
    __shared__ float red[8];
    const int tid = threadIdx.x;
    const int wave = tid >> 6, lane = tid & 63;
    const int i = blockIdx.x * 4 + wave;
    float num = 0.f, den = 0.f;

    if (i < NN) {
        int s = rp[i], e = rp[i + 1];
        float a0 = 0.f, a1 = 0.f, a2 = 0.f, a3 = 0.f;
        int k = s, m4 = s + ((e - s) & ~3);
        for (; k < m4; k += 4) {
            int n0 = csr[k], n1 = csr[k + 1], n2 = csr[k + 2], n3 = csr[k + 3];
            a0 += z[(size_t)n0 * 96 + lane];
            a1 += z[(size_t)n1 * 96 + lane];
            a2 += z[(size_t)n2 * 96 + lane];
            a3 += z[(size_t)n3 * 96 + lane];
        }
        for (; k < e; ++k) a0 += z[(size_t)csr[k] * 96 + lane];
        float agg = (a0 + a1) + (a2 + a3);

        float logit;
        if (lane < CC) {
            float zsv = z[(size_t)i * 96 + 48 + lane];
            logit = agg * inv[i] + zsv + b2n[lane] + b2s[lane];
        } else {
            logit = -1e30f;
        }
        float mx = logit;
#pragma unroll
        for (int off = 32; off >= 1; off >>= 1)
            mx = fmaxf(mx, __shfl_xor(mx, off));
        float ex = (lane < CC) ? __expf(logit - mx) : 0.f;
        float sm = ex;
#pragma unroll
        for (int off = 32; off >= 1; off >>= 1)
            sm += __shfl_xor(sm, off);
        float lse = mx + __logf(sm);
        int yi = y[i];
        float ly = __shfl(logit, yi);
        if (lane == 0 && mask[i]) { num = lse - ly; den = 1.f; }
    }
    if (lane == 0) { red[wave * 2] = num; red[wave * 2 + 1] = den; }
    __syncthreads();
    if (tid == 0) {
        atomicAdd(&accum[0], red[0] + red[2] + red[4] + red[6]);
        atomicAdd(&accum[1], red[1] + red[3] + red[5] + red[7]);
    }
}

__global__ void finalize_kernel(const float* __restrict__ accum, float* __restrict__ out) {
    out[0] = accum[0] / fmaxf(accum[1], 1.0f);
}

// ---------------------------------------------------------------- launch
extern "C" void kernel_launch(void* const* d_in, const int* in_sizes, int n_in,
                              void* d_out, int out_size, void* d_ws, size_t ws_size,
                              hipStream_t stream) {
    const float* x   = (const float*)d_in[0];
    const int*   row = (const int*)d_in[1];
    const int*   col = (const int*)d_in[2];
    const int*   y   = (const int*)d_in[3];
    const int*   msk = (const int*)d_in[4];
    const float* w1n = (const float*)d_in[5];
    const float* b1n = (const float*)d_in[6];
    const float* w1s = (const float*)d_in[7];
    const float* b1s = (const float*)d_in[8];
    const float* w2n = (const float*)d_in[9];
    const float* b2n = (const float*)d_in[10];
    const float* w2s = (const float*)d_in[11];
    const float* b2s = (const float*)d_in[12];
    float* out = (float*)d_out;

    float* ws      = (float*)d_ws;
    float* accum   = ws;                                  // 64 f
    int*   deg     = (int*)(ws + 64);                     // 50048
    int*   row_ptr = deg + 50048;                         // 50048
    int*   cursor  = row_ptr + 50048;                     // 50048
    int*   partial = cursor + 50048;                      // 256
    int*   csr     = partial + 256;                       // 800000
    float* inv     = (float*)(csr + 800000);              // 50048
    unsigned* xb   = (unsigned*)(inv + 50048);            // NN*64
    unsigned* ab   = xb + (size_t)NN * 64;                // NN*128 (=[a|x] bf16)
    unsigned short* h1b = (unsigned short*)(ab + (size_t)NN * 128);  // NN*256 bf16
    float* z       = (float*)(h1b + (size_t)NN * 256);    // NN*96
    unsigned short* WB1 = (unsigned short*)(z + (size_t)NN * 96);    // 256*256
    unsigned short* WB2 = WB1 + 65536;                    // 96*256
    float* bias1   = (float*)(WB2 + 24576);               // 256

    const int NBLK = (NN + 255) / 256;    // 196

    (void)hipMemsetAsync(accum, 0, (64 + 50048) * sizeof(float), stream);  // accum + deg

    deg_kernel<<<(EE + 255) / 256, 256, 0, stream>>>(row, deg);
    scan1<<<NBLK, 256, 0, stream>>>(deg, row_ptr, partial);
    scan2<<<1, 256, 0, stream>>>(partial, NBLK);
    scan3<<<NBLK, 256, 0, stream>>>(deg, row_ptr, partial, cursor, inv);
    fill_kernel<<<(EE + 255) / 256, 256, 0, stream>>>(row, col, cursor, csr);

    convert_x<<<(NN * 64 + 255) / 256, 256, 0, stream>>>(x, xb, ab);
    repack_w<<<(65536 + 24576 + 256 + 255) / 256, 256, 0, stream>>>(
        w1n, w1s, b1n, b1s, w2n, w2s, WB1, WB2, bias1);

    agg1<<<(NN + 3) / 4, 256, 0, stream>>>(xb, row_ptr, csr, inv, ab);

    dim3 g1((NN + 63) / 64, 4);
    gemm1_mfma<<<g1, 256, 0, stream>>>((const unsigned short*)ab, WB1, bias1, h1b);

    dim3 g2((NN + 63) / 64, 2);
    gemm2_mfma<<<g2, 256, 0, stream>>>(h1b, WB2, z);

    loss_kernel<<<(NN + 3) / 4, 256, 0, stream>>>(
        z, row_ptr, csr, inv, b2n, b2s, y, msk, accum);

    finalize_kernel<<<1, 1, 0, stream>>>(accum, out);
}

// Round 6
// 603.270 us; speedup vs baseline: 7.3994x; 1.0203x over previous
//
#include <hip/hip_runtime.h>
#include <math.h>

#define NN 50000
#define EE 800000
#define DIN 128
#define HH 256
#define CC 47
#define LK2 264   // LDS row stride in bf16 (256 + 8 pad)

typedef short bf16x8 __attribute__((ext_vector_type(8)));
typedef float f32x4 __attribute__((ext_vector_type(4)));

static __device__ __forceinline__ unsigned short f2bf(float f) {
    unsigned u = __float_as_uint(f);
    u = u + 0x7fff + ((u >> 16) & 1);
    return (unsigned short)(u >> 16);
}
static __device__ __forceinline__ float bflo(unsigned u) { return __uint_as_float(u << 16); }
static __device__ __forceinline__ float bfhi(unsigned u) { return __uint_as_float(u & 0xffff0000u); }

// ---------------------------------------------------------------- degree
__global__ __launch_bounds__(256) void deg_kernel(const int* __restrict__ row,
                                                  int* __restrict__ deg) {
    int t = blockIdx.x * 256 + threadIdx.x;
    if (t < EE) atomicAdd(&deg[row[t]], 1);
}

// ------------------------------------------------------- exclusive scan (3k)
__global__ __launch_bounds__(256) void scan1(const int* __restrict__ deg,
                                             int* __restrict__ row_ptr,
                                             int* __restrict__ partial) {
    __shared__ int tot[4], pre[4];
    int tid = threadIdx.x, t = blockIdx.x * 256 + tid;
    int lane = tid & 63, wave = tid >> 6;
    int v = (t < NN) ? deg[t] : 0;
    int incl = v;
#pragma unroll
    for (int off = 1; off < 64; off <<= 1) {
        int u = __shfl_up(incl, off);
        if (lane >= off) incl += u;
    }
    if (lane == 63) tot[wave] = incl;
    __syncthreads();
    if (tid == 0) {
        int s = 0;
#pragma unroll
        for (int w = 0; w < 4; ++w) { pre[w] = s; s += tot[w]; }
        partial[blockIdx.x] = s;
    }
    __syncthreads();
    if (t < NN) row_ptr[t] = incl - v + pre[wave];
}

__global__ __launch_bounds__(256) void scan2(int* __restrict__ partial, int nblk) {
    __shared__ int tot[4], pre[4];
    int tid = threadIdx.x;
    int lane = tid & 63, wave = tid >> 6;
    int v = (tid < nblk) ? partial[tid] : 0;
    int incl = v;
#pragma unroll
    for (int off = 1; off < 64; off <<= 1) {
        int u = __shfl_up(incl, off);
        if (lane >= off) incl += u;
    }
    if (lane == 63) tot[wave] = incl;
    __syncthreads();
    if (tid == 0) {
        int s = 0;
#pragma unroll
        for (int w = 0; w < 4; ++w) { pre[w] = s; s += tot[w]; }
    }
    __syncthreads();
    partial[tid] = incl - v + pre[wave];
}

__global__ __launch_bounds__(256) void scan3(const int* __restrict__ deg,
                                             int* __restrict__ row_ptr,
                                             const int* __restrict__ partial,
                                             int* __restrict__ cursor,
                                             float* __restrict__ inv) {
    int t = blockIdx.x * 256 + threadIdx.x;
    if (t < NN) {
        int rp = row_ptr[t] + partial[blockIdx.x];
        row_ptr[t] = rp;
        cursor[t] = rp;
        inv[t] = 1.0f / fmaxf((float)deg[t], 1.0f);
    }
    if (t == 0) row_ptr[NN] = EE;
}

__global__ __launch_bounds__(256) void fill_kernel(const int* __restrict__ row,
                                                   const int* __restrict__ col,
                                                   int* __restrict__ cursor,
                                                   int* __restrict__ csr) {
    int e = blockIdx.x * 256 + threadIdx.x;
    if (e < EE) {
        int r = row[e];
        int pos = atomicAdd(&cursor[r], 1);
        csr[pos] = col[e];
    }
}

// ------------------------------------------------- x -> bf16 (xb and ab[:,128:])
__global__ __launch_bounds__(256) void convert_x(const float* __restrict__ x,
                                                 unsigned* __restrict__ xb,
                                                 unsigned* __restrict__ ab) {
    int t = blockIdx.x * 256 + threadIdx.x;      // one per bf16 pair
    if (t >= NN * 64) return;
    int i = t >> 6, l = t & 63;
    float2 v = *(const float2*)&x[(size_t)i * DIN + l * 2];
    unsigned p = (unsigned)f2bf(v.x) | ((unsigned)f2bf(v.y) << 16);
    xb[t] = p;
    ab[(size_t)i * 128 + 64 + l] = p;
}

// --------------------------------------------------- weight repack (bf16, [n][k])
__global__ __launch_bounds__(256) void repack_w(
    const float* __restrict__ w1n, const float* __restrict__ w1s,
    const float* __restrict__ b1n, const float* __restrict__ b1s,
    const float* __restrict__ w2n, const float* __restrict__ w2s,
    unsigned short* __restrict__ WB1, unsigned short* __restrict__ WB2,
    float* __restrict__ bias1)
{
    int t = blockIdx.x * 256 + threadIdx.x;
    if (t < 65536) {
        int n = t >> 8, k = t & 255;
        float v = (k < 128) ? w1n[k * HH + n] : w1s[(k - 128) * HH + n];
        WB1[n * 256 + k] = f2bf(v);
    } else if (t < 65536 + 24576) {
        int q = t - 65536;
        int n = q >> 8, k = q & 255;
        float v;
        if (n < 48) v = (n < CC) ? w2n[k * CC + n] : 0.f;
        else { int m = n - 48; v = (m < CC) ? w2s[k * CC + m] : 0.f; }
        WB2[n * 256 + k] = f2bf(v);
    } else if (t < 65536 + 24576 + 256) {
        int n = t - 65536 - 24576;
        bias1[n] = b1n[n] + b1s[n];
    }
}

// ----------------------------------------------- layer-1 gather aggregation
// wave per node; lane owns one xb dword (2 feats). CSR lane-preload + 8-deep.
__global__ __launch_bounds__(256) void agg1(const unsigned* __restrict__ xb,
                                            const int* __restrict__ rp,
                                            const int* __restrict__ csr,
                                            const float* __restrict__ inv,
                                            unsigned* __restrict__ ab) {
    int wave = threadIdx.x >> 6, lane = threadIdx.x & 63;
    int i = blockIdx.x * 4 + wave;
    if (i >= NN) return;
    int s = rp[i], e = rp[i + 1];
    float x0 = 0, y0 = 0, x1 = 0, y1 = 0, x2 = 0, y2 = 0, x3 = 0, y3 = 0;
    for (int base = s; base < e; base += 64) {
        int cnt = min(64, e - base);
        int myidx = csr[min(base + lane, e - 1)];
        int j = 0;
        for (; j + 8 <= cnt; j += 8) {
            int n0 = __shfl(myidx, j + 0), n1 = __shfl(myidx, j + 1);
            int n2 = __shfl(myidx, j + 2), n3 = __shfl(myidx, j + 3);
            int n4 = __shfl(myidx, j + 4), n5 = __shfl(myidx, j + 5);
            int n6 = __shfl(myidx, j + 6), n7 = __shfl(myidx, j + 7);
            unsigned u0 = xb[(size_t)n0 * 64 + lane];
            unsigned u1 = xb[(size_t)n1 * 64 + lane];
            unsigned u2 = xb[(size_t)n2 * 64 + lane];
            unsigned u3 = xb[(size_t)n3 * 64 + lane];
            unsigned u4 = xb[(size_t)n4 * 64 + lane];
            unsigned u5 = xb[(size_t)n5 * 64 + lane];
            unsigned u6 = xb[(size_t)n6 * 64 + lane];
            unsigned u7 = xb[(size_t)n7 * 64 + lane];
            x0 += bflo(u0); y0 += bfhi(u0); x1 += bflo(u1); y1 += bfhi(u1);
            x2 += bflo(u2); y2 += bfhi(u2); x3 += bflo(u3); y3 += bfhi(u3);
            x0 += bflo(u4); y0 += bfhi(u4); x1 += bflo(u5); y1 += bfhi(u5);
            x2 += bflo(u6); y2 += bfhi(u6); x3 += bflo(u7); y3 += bfhi(u7);
        }
        for (; j < cnt; ++j) {
            int n = __shfl(myidx, j);
            unsigned u = xb[(size_t)n * 64 + lane];
            x0 += bflo(u); y0 += bfhi(u);
        }
    }
    float sc = inv[i];
    float ax = ((x0 + x1) + (x2 + x3)) * sc;
    float ay = ((y0 + y1) + (y2 + y3)) * sc;
    ab[(size_t)i * 128 + lane] = (unsigned)f2bf(ax) | ((unsigned)f2bf(ay) << 16);
}

// ------------------------------------------------------- layer-1 MFMA GEMM
__global__ __launch_bounds__(256) void gemm1_mfma(
    const unsigned short* __restrict__ AB, const unsigned short* __restrict__ WB1,
    const float* __restrict__ bias1, unsigned short* __restrict__ h1b)
{
    __shared__ unsigned short sA[64 * LK2];
    __shared__ unsigned short sB[64 * LK2];
    const int tid = threadIdx.x;
    const int i0 = blockIdx.x * 64;
    const int n0 = blockIdx.y * 64;
    const int wv = tid >> 6, lane = tid & 63;
    const int g = lane >> 4, l16 = lane & 15;
    const int m0 = (wv >> 1) * 32, q0 = (wv & 1) * 32;

    f32x4 acc00 = {}, acc01 = {}, acc10 = {}, acc11 = {};

#pragma unroll
    for (int l = 0; l < 8; ++l) {
        int c = tid + l * 256;              // 0..2047
        int r = c >> 5, c8 = (c & 31) * 8;
        int gi = i0 + r;
        int4 v = make_int4(0, 0, 0, 0);
        if (gi < NN) v = *(const int4*)&AB[(size_t)gi * 256 + c8];
        *(int4*)&sA[r * LK2 + c8] = v;
        int4 w = *(const int4*)&WB1[(size_t)(n0 + r) * 256 + c8];
        *(int4*)&sB[r * LK2 + c8] = w;
    }
    __syncthreads();
#pragma unroll
    for (int kk = 0; kk < 256; kk += 32) {
        bf16x8 a0 = *(const bf16x8*)&sA[(m0 + l16) * LK2 + kk + g * 8];
        bf16x8 a1 = *(const bf16x8*)&sA[(m0 + 16 + l16) * LK2 + kk + g * 8];
        bf16x8 b0 = *(const bf16x8*)&sB[(q0 + l16) * LK2 + kk + g * 8];
        bf16x8 b1 = *(const bf16x8*)&sB[(q0 + 16 + l16) * LK2 + kk + g * 8];
        acc00 = __builtin_amdgcn_mfma_f32_16x16x32_bf16(a0, b0, acc00, 0, 0, 0);
        acc01 = __builtin_amdgcn_mfma_f32_16x16x32_bf16(a0, b1, acc01, 0, 0, 0);
        acc10 = __builtin_amdgcn_mfma_f32_16x16x32_bf16(a1, b0, acc10, 0, 0, 0);
        acc11 = __builtin_amdgcn_mfma_f32_16x16x32_bf16(a1, b1, acc11, 0, 0, 0);
    }
    int colA = n0 + q0 + l16;
    int colB = colA + 16;
    float bA = bias1[colA], bB = bias1[colB];
#pragma unroll
    for (int r = 0; r < 4; ++r) {
        int rowi = g * 4 + r;
        int giA = i0 + m0 + rowi;
        int giB = giA + 16;
        if (giA < NN) {
            h1b[(size_t)giA * 256 + colA] = f2bf(fmaxf(acc00[r] + bA, 0.f));
            h1b[(size_t)giA * 256 + colB] = f2bf(fmaxf(acc01[r] + bB, 0.f));
        }
        if (giB < NN) {
            h1b[(size_t)giB * 256 + colA] = f2bf(fmaxf(acc10[r] + bA, 0.f));
            h1b[(size_t)giB * 256 + colB] = f2bf(fmaxf(acc11[r] + bB, 0.f));
        }
    }
}

// ------------------------------------------------------- layer-2 MFMA GEMM
// blockIdx.y==0: zn = h1@w2n -> packed bf16 (48 cols, 24 dwords/row)
// blockIdx.y==1: zsb = h1@w2s + bias2 -> fp32 (48 cols/row)
__global__ __launch_bounds__(256) void gemm2_mfma(
    const unsigned short* __restrict__ h1b, const unsigned short* __restrict__ WB2,
    const float* __restrict__ b2n, const float* __restrict__ b2s,
    unsigned* __restrict__ znb, float* __restrict__ zsb)
{
    __shared__ unsigned short sA[64 * LK2];
    __shared__ unsigned short sB[48 * LK2];
    const int tid = threadIdx.x;
    const int i0 = blockIdx.x * 64;
    const int n0 = blockIdx.y * 48;
    const int wv = tid >> 6, lane = tid & 63;
    const int g = lane >> 4, l16 = lane & 15;
    const int m0 = wv * 16;
    f32x4 acc[3] = {};

#pragma unroll
    for (int l = 0; l < 8; ++l) {
        int c = tid + l * 256;
        int r = c >> 5, c8 = (c & 31) * 8;
        int gi = i0 + r;
        int4 v = make_int4(0, 0, 0, 0);
        if (gi < NN) v = *(const int4*)&h1b[(size_t)gi * 256 + c8];
        *(int4*)&sA[r * LK2 + c8] = v;
    }
#pragma unroll
    for (int l = 0; l < 6; ++l) {
        int c = tid + l * 256;
        int r = c >> 5, c8 = (c & 31) * 8;
        *(int4*)&sB[r * LK2 + c8] = *(const int4*)&WB2[(size_t)(n0 + r) * 256 + c8];
    }
    __syncthreads();
#pragma unroll
    for (int kk = 0; kk < 256; kk += 32) {
        bf16x8 af = *(const bf16x8*)&sA[(m0 + l16) * LK2 + kk + g * 8];
#pragma unroll
        for (int ni = 0; ni < 3; ++ni) {
            bf16x8 bfv = *(const bf16x8*)&sB[(ni * 16 + l16) * LK2 + kk + g * 8];
            acc[ni] = __builtin_amdgcn_mfma_f32_16x16x32_bf16(af, bfv, acc[ni], 0, 0, 0);
        }
    }
    if (blockIdx.y == 0) {
#pragma unroll
        for (int ni = 0; ni < 3; ++ni) {
#pragma unroll
            for (int r = 0; r < 4; ++r) {
                int gi = i0 + m0 + g * 4 + r;
                float v = acc[ni][r];
                float vp = __shfl_down(v, 1);
                if (((l16 & 1) == 0) && gi < NN)
                    znb[(size_t)gi * 24 + ni * 8 + (l16 >> 1)] =
                        (unsigned)f2bf(v) | ((unsigned)f2bf(vp) << 16);
            }
        }
    } else {
#pragma unroll
        for (int ni = 0; ni < 3; ++ni) {
            int c = ni * 16 + l16;
            float bias = (c < CC) ? (b2n[c] + b2s[c]) : 0.f;
#pragma unroll
            for (int r = 0; r < 4; ++r) {
                int gi = i0 + m0 + g * 4 + r;
                if (gi < NN) zsb[(size_t)gi * 48 + c] = acc[ni][r] + bias;
            }
        }
    }
}

// ----------------------- packed-bf16 gather-aggregate + log_softmax + NLL
// wave per node; lanes 0-23 gather even edges, 32-55 odd edges (2 classes/lane).
__global__ __launch_bounds__(256) void loss_kernel(
    const unsigned* __restrict__ znb, const float* __restrict__ zsb,
    const int* __restrict__ rp, const int* __restrict__ csr,
    const float* __restrict__ inv,
    const int* __restrict__ y, const int* __restrict__ mask,
    float* __restrict__ accum)
{
    __shared__ float red[8];
    const int tid = threadIdx.x;
    const int wave = tid >> 6, lane = tid & 63;
    const int half = lane >> 5, hl = lane & 31;
    const bool active = hl < 24;
    const int dw = active ? hl : 0;
    const int i = blockIdx.x * 4 + wave;
    float num = 0.f, den = 0.f;

    if (i < NN) {
        int s = rp[i], e = rp[i + 1];
        float alo = 0.f, ahi = 0.f, blo = 0.f, bhi = 0.f;
        float clo = 0.f, chi = 0.f, dlo = 0.f, dhi = 0.f;
        for (int base = s; base < e; base += 64) {
            int cnt = min(64, e - base);
            int myidx = csr[min(base + lane, e - 1)];
            int j = 0;
            for (; j + 8 <= cnt; j += 8) {
                int n0 = __shfl(myidx, j + 0 + half);
                int n1 = __shfl(myidx, j + 2 + half);
                int n2 = __shfl(myidx, j + 4 + half);
                int n3 = __shfl(myidx, j + 6 + half);
                unsigned u0 = znb[(size_t)n0 * 24 + dw];
                unsigned u1 = znb[(size_t)n1 * 24 + dw];
                unsigned u2 = znb[(size_t)n2 * 24 + dw];
                unsigned u3 = znb[(size_t)n3 * 24 + dw];
                if (!active) { u0 = u1 = u2 = u3 = 0u; }
                alo += bflo(u0); ahi += bfhi(u0);
                blo += bflo(u1); bhi += bfhi(u1);
                clo += bflo(u2); chi += bfhi(u2);
                dlo += bflo(u3); dhi += bfhi(u3);
            }
            for (; j < cnt; j += 2) {
                int src = j + half;
                int nn = __shfl(myidx, min(src, cnt - 1));
                unsigned u = znb[(size_t)nn * 24 + dw];
                if (!active || src >= cnt) u = 0u;
                alo += bflo(u); ahi += bfhi(u);
            }
        }
        alo = (alo + blo) + (clo + dlo);
        ahi = (ahi + bhi) + (chi + dhi);
        alo += __shfl_xor(alo, 32);
        ahi += __shfl_xor(ahi, 32);
        float sc = inv[i];
        float llo = -1e30f, lhi = -1e30f;
        if (active) {
            llo = alo * sc + zsb[(size_t)i * 48 + 2 * hl];
            lhi = ahi * sc + zsb[(size_t)i * 48 + 2 * hl + 1];
        }
        if (hl == 23) lhi = -1e30f;      // class 47 invalid
        float mx = fmaxf(llo, lhi);
#pragma unroll
        for (int off = 16; off >= 1; off >>= 1)
            mx = fmaxf(mx, __shfl_xor(mx, off));
        float ex = active ? (__expf(llo - mx) + __expf(lhi - mx)) : 0.f;
        float sm = ex;
#pragma unroll
        for (int off = 16; off >= 1; off >>= 1)
            sm += __shfl_xor(sm, off);
        float lse = mx + __logf(sm);
        int yi = y[i];
        float gl = __shfl(llo, yi >> 1);
        float gh = __shfl(lhi, yi >> 1);
        float ly = (yi & 1) ? gh : gl;
        if (lane == 0 && mask[i]) { num = lse - ly; den = 1.f; }
    }
    if (lane == 0) { red[wave * 2] = num; red[wave * 2 + 1] = den; }
    __syncthreads();
    if (tid == 0) {
        atomicAdd(&accum[0], red[0] + red[2] + red[4] + red[6]);
        atomicAdd(&accum[1], red[1] + red[3] + red[5] + red[7]);
    }
}

__global__ void finalize_kernel(const float* __restrict__ accum, float* __restrict__ out) {
    out[0] = accum[0] / fmaxf(accum[1], 1.0f);
}

// ---------------------------------------------------------------- launch
extern "C" void kernel_launch(void* const* d_in, const int* in_sizes, int n_in,
                              void* d_out, int out_size, void* d_ws, size_t ws_size,
                              hipStream_t stream) {
    const float* x   = (const float*)d_in[0];
    const int*   row = (const int*)d_in[1];
    const int*   col = (const int*)d_in[2];
    const int*   y   = (const int*)d_in[3];
    const int*   msk = (const int*)d_in[4];
    const float* w1n = (const float*)d_in[5];
    const float* b1n = (const float*)d_in[6];
    const float* w1s = (const float*)d_in[7];
    const float* b1s = (const float*)d_in[8];
    const float* w2n = (const float*)d_in[9];
    const float* b2n = (const float*)d_in[10];
    const float* w2s = (const float*)d_in[11];
    const float* b2s = (const float*)d_in[12];
    float* out = (float*)d_out;

    float* ws      = (float*)d_ws;
    float* accum   = ws;                                  // 64 f
    int*   deg     = (int*)(ws + 64);                     // 50048
    int*   row_ptr = deg + 50048;                         // 50048
    int*   cursor  = row_ptr + 50048;                     // 50048
    int*   partial = cursor + 50048;                      // 256
    int*   csr     = partial + 256;                       // 800000
    float* inv     = (float*)(csr + 800000);              // 50048
    unsigned* xb   = (unsigned*)(inv + 50048);            // NN*64
    unsigned* ab   = xb + (size_t)NN * 64;                // NN*128 (=[a|x] bf16)
    unsigned short* h1b = (unsigned short*)(ab + (size_t)NN * 128);  // NN*256 bf16
    unsigned* znb  = (unsigned*)(h1b + (size_t)NN * 256); // NN*24 (48 bf16)
    float* zsb     = (float*)(znb + (size_t)NN * 24);     // NN*48 fp32
    unsigned short* WB1 = (unsigned short*)(zsb + (size_t)NN * 48);  // 256*256
    unsigned short* WB2 = WB1 + 65536;                    // 96*256
    float* bias1   = (float*)(WB2 + 24576);               // 256

    const int NBLK = (NN + 255) / 256;    // 196

    (void)hipMemsetAsync(accum, 0, (64 + 50048) * sizeof(float), stream);  // accum + deg

    deg_kernel<<<(EE + 255) / 256, 256, 0, stream>>>(row, deg);
    scan1<<<NBLK, 256, 0, stream>>>(deg, row_ptr, partial);
    scan2<<<1, 256, 0, stream>>>(partial, NBLK);
    scan3<<<NBLK, 256, 0, stream>>>(deg, row_ptr, partial, cursor, inv);
    fill_kernel<<<(EE + 255) / 256, 256, 0, stream>>>(row, col, cursor, csr);

    convert_x<<<(NN * 64 + 255) / 256, 256, 0, stream>>>(x, xb, ab);
    repack_w<<<(65536 + 24576 + 256 + 255) / 256, 256, 0, stream>>>(
        w1n, w1s, b1n, b1s, w2n, w2s, WB1, WB2, bias1);

    agg1<<<(NN + 3) / 4, 256, 0, stream>>>(xb, row_ptr, csr, inv, ab);

    dim3 g1((NN + 63) / 64, 4);
    gemm1_mfma<<<g1, 256, 0, stream>>>((const unsigned short*)ab, WB1, bias1, h1b);

    dim3 g2((NN + 63) / 64, 2);
    gemm2_mfma<<<g2, 256, 0, stream>>>(h1b, WB2, b2n, b2s, znb, zsb);

    loss_kernel<<<(NN + 3) / 4, 256, 0, stream>>>(
        znb, zsb, row_ptr, csr, inv, y, msk, accum);

    finalize_kernel<<<1, 1, 0, stream>>>(accum, out);
}

// Round 7
// 359.252 us; speedup vs baseline: 12.4253x; 1.6792x over previous
//
#include <hip/hip_runtime.h>
#include <math.h>

#define NN 50000
#define EE 800000
#define DIN 128
#define HH 256
#define CC 47
#define LK2 264   // LDS row stride in bf16 (256 + 8 pad)
#define GS_BLOCKS 2048   // grid-stride blocks: 8192 waves = max residency

typedef short bf16x8 __attribute__((ext_vector_type(8)));
typedef float f32x4 __attribute__((ext_vector_type(4)));

static __device__ __forceinline__ unsigned short f2bf(float f) {
    unsigned u = __float_as_uint(f);
    u = u + 0x7fff + ((u >> 16) & 1);
    return (unsigned short)(u >> 16);
}
static __device__ __forceinline__ float bflo(unsigned u) { return __uint_as_float(u << 16); }
static __device__ __forceinline__ float bfhi(unsigned u) { return __uint_as_float(u & 0xffff0000u); }

// ---------------------------------------------------------------- degree
__global__ __launch_bounds__(256) void deg_kernel(const int* __restrict__ row,
                                                  int* __restrict__ deg) {
    int t = blockIdx.x * 256 + threadIdx.x;
    if (t < EE) atomicAdd(&deg[row[t]], 1);
}

// ------------------------------------------------------- exclusive scan (3k)
__global__ __launch_bounds__(256) void scan1(const int* __restrict__ deg,
                                             int* __restrict__ row_ptr,
                                             int* __restrict__ partial) {
    __shared__ int tot[4], pre[4];
    int tid = threadIdx.x, t = blockIdx.x * 256 + tid;
    int lane = tid & 63, wave = tid >> 6;
    int v = (t < NN) ? deg[t] : 0;
    int incl = v;
#pragma unroll
    for (int off = 1; off < 64; off <<= 1) {
        int u = __shfl_up(incl, off);
        if (lane >= off) incl += u;
    }
    if (lane == 63) tot[wave] = incl;
    __syncthreads();
    if (tid == 0) {
        int s = 0;
#pragma unroll
        for (int w = 0; w < 4; ++w) { pre[w] = s; s += tot[w]; }
        partial[blockIdx.x] = s;
    }
    __syncthreads();
    if (t < NN) row_ptr[t] = incl - v + pre[wave];
}

__global__ __launch_bounds__(256) void scan2(int* __restrict__ partial, int nblk) {
    __shared__ int tot[4], pre[4];
    int tid = threadIdx.x;
    int lane = tid & 63, wave = tid >> 6;
    int v = (tid < nblk) ? partial[tid] : 0;
    int incl = v;
#pragma unroll
    for (int off = 1; off < 64; off <<= 1) {
        int u = __shfl_up(incl, off);
        if (lane >= off) incl += u;
    }
    if (lane == 63) tot[wave] = incl;
    __syncthreads();
    if (tid == 0) {
        int s = 0;
#pragma unroll
        for (int w = 0; w < 4; ++w) { pre[w] = s; s += tot[w]; }
    }
    __syncthreads();
    partial[tid] = incl - v + pre[wave];
}

__global__ __launch_bounds__(256) void scan3(const int* __restrict__ deg,
                                             int* __restrict__ row_ptr,
                                             const int* __restrict__ partial,
                                             int* __restrict__ cursor,
                                             float* __restrict__ inv) {
    int t = blockIdx.x * 256 + threadIdx.x;
    if (t < NN) {
        int rp = row_ptr[t] + partial[blockIdx.x];
        row_ptr[t] = rp;
        cursor[t] = rp;
        inv[t] = 1.0f / fmaxf((float)deg[t], 1.0f);
    }
    if (t == 0) row_ptr[NN] = EE;
}

__global__ __launch_bounds__(256) void fill_kernel(const int* __restrict__ row,
                                                   const int* __restrict__ col,
                                                   int* __restrict__ cursor,
                                                   int* __restrict__ csr) {
    int e = blockIdx.x * 256 + threadIdx.x;
    if (e < EE) {
        int r = row[e];
        int pos = atomicAdd(&cursor[r], 1);
        csr[pos] = col[e];
    }
}

// ------------------------------------------------- x -> bf16 (xb and ab[:,128:])
__global__ __launch_bounds__(256) void convert_x(const float* __restrict__ x,
                                                 unsigned* __restrict__ xb,
                                                 unsigned* __restrict__ ab) {
    int t = blockIdx.x * 256 + threadIdx.x;      // one per bf16 pair
    if (t >= NN * 64) return;
    int i = t >> 6, l = t & 63;
    float2 v = *(const float2*)&x[(size_t)i * DIN + l * 2];
    unsigned p = (unsigned)f2bf(v.x) | ((unsigned)f2bf(v.y) << 16);
    xb[t] = p;
    ab[(size_t)i * 128 + 64 + l] = p;
}

// --------------------------------------------------- weight repack (bf16, [n][k])
__global__ __launch_bounds__(256) void repack_w(
    const float* __restrict__ w1n, const float* __restrict__ w1s,
    const float* __restrict__ b1n, const float* __restrict__ b1s,
    const float* __restrict__ w2n, const float* __restrict__ w2s,
    unsigned short* __restrict__ WB1, unsigned short* __restrict__ WB2,
    float* __restrict__ bias1)
{
    int t = blockIdx.x * 256 + threadIdx.x;
    if (t < 65536) {
        int n = t >> 8, k = t & 255;
        float v = (k < 128) ? w1n[k * HH + n] : w1s[(k - 128) * HH + n];
        WB1[n * 256 + k] = f2bf(v);
    } else if (t < 65536 + 24576) {
        int q = t - 65536;
        int n = q >> 8, k = q & 255;
        float v;
        if (n < 48) v = (n < CC) ? w2n[k * CC + n] : 0.f;
        else { int m = n - 48; v = (m < CC) ? w2s[k * CC + m] : 0.f; }
        WB2[n * 256 + k] = f2bf(v);
    } else if (t < 65536 + 24576 + 256) {
        int n = t - 65536 - 24576;
        bias1[n] = b1n[n] + b1s[n];
    }
}

// ----------------------------------------------- layer-1 gather aggregation
// grid-stride: wave per node; lane owns one xb dword (2 feats).
__global__ __launch_bounds__(256) void agg1(const unsigned* __restrict__ xb,
                                            const int* __restrict__ rp,
                                            const int* __restrict__ csr,
                                            const float* __restrict__ inv,
                                            unsigned* __restrict__ ab) {
    int wave = threadIdx.x >> 6, lane = threadIdx.x & 63;
    const int W = gridDim.x * 4;
    for (int i = blockIdx.x * 4 + wave; i < NN; i += W) {
        int s = rp[i], e = rp[i + 1];
        float x0 = 0, y0 = 0, x1 = 0, y1 = 0, x2 = 0, y2 = 0, x3 = 0, y3 = 0;
        for (int base = s; base < e; base += 64) {
            int cnt = min(64, e - base);
            int myidx = csr[min(base + lane, e - 1)];
            int j = 0;
            for (; j + 8 <= cnt; j += 8) {
                int n0 = __shfl(myidx, j + 0), n1 = __shfl(myidx, j + 1);
                int n2 = __shfl(myidx, j + 2), n3 = __shfl(myidx, j + 3);
                int n4 = __shfl(myidx, j + 4), n5 = __shfl(myidx, j + 5);
                int n6 = __shfl(myidx, j + 6), n7 = __shfl(myidx, j + 7);
                unsigned u0 = xb[(size_t)n0 * 64 + lane];
                unsigned u1 = xb[(size_t)n1 * 64 + lane];
                unsigned u2 = xb[(size_t)n2 * 64 + lane];
                unsigned u3 = xb[(size_t)n3 * 64 + lane];
                unsigned u4 = xb[(size_t)n4 * 64 + lane];
                unsigned u5 = xb[(size_t)n5 * 64 + lane];
                unsigned u6 = xb[(size_t)n6 * 64 + lane];
                unsigned u7 = xb[(size_t)n7 * 64 + lane];
                x0 += bflo(u0); y0 += bfhi(u0); x1 += bflo(u1); y1 += bfhi(u1);
                x2 += bflo(u2); y2 += bfhi(u2); x3 += bflo(u3); y3 += bfhi(u3);
                x0 += bflo(u4); y0 += bfhi(u4); x1 += bflo(u5); y1 += bfhi(u5);
                x2 += bflo(u6); y2 += bfhi(u6); x3 += bflo(u7); y3 += bfhi(u7);
            }
            for (; j < cnt; ++j) {
                int n = __shfl(myidx, j);
                unsigned u = xb[(size_t)n * 64 + lane];
                x0 += bflo(u); y0 += bfhi(u);
            }
        }
        float sc = inv[i];
        float ax = ((x0 + x1) + (x2 + x3)) * sc;
        float ay = ((y0 + y1) + (y2 + y3)) * sc;
        ab[(size_t)i * 128 + lane] = (unsigned)f2bf(ax) | ((unsigned)f2bf(ay) << 16);
    }
}

// ------------------------------------------------------- layer-1 MFMA GEMM
__global__ __launch_bounds__(256) void gemm1_mfma(
    const unsigned short* __restrict__ AB, const unsigned short* __restrict__ WB1,
    const float* __restrict__ bias1, unsigned short* __restrict__ h1b)
{
    __shared__ unsigned short sA[64 * LK2];
    __shared__ unsigned short sB[64 * LK2];
    const int tid = threadIdx.x;
    const int i0 = blockIdx.x * 64;
    const int n0 = blockIdx.y * 64;
    const int wv = tid >> 6, lane = tid & 63;
    const int g = lane >> 4, l16 = lane & 15;
    const int m0 = (wv >> 1) * 32, q0 = (wv & 1) * 32;

    f32x4 acc00 = {}, acc01 = {}, acc10 = {}, acc11 = {};

#pragma unroll
    for (int l = 0; l < 8; ++l) {
        int c = tid + l * 256;              // 0..2047
        int r = c >> 5, c8 = (c & 31) * 8;
        int gi = i0 + r;
        int4 v = make_int4(0, 0, 0, 0);
        if (gi < NN) v = *(const int4*)&AB[(size_t)gi * 256 + c8];
        *(int4*)&sA[r * LK2 + c8] = v;
        int4 w = *(const int4*)&WB1[(size_t)(n0 + r) * 256 + c8];
        *(int4*)&sB[r * LK2 + c8] = w;
    }
    __syncthreads();
#pragma unroll
    for (int kk = 0; kk < 256; kk += 32) {
        bf16x8 a0 = *(const bf16x8*)&sA[(m0 + l16) * LK2 + kk + g * 8];
        bf16x8 a1 = *(const bf16x8*)&sA[(m0 + 16 + l16) * LK2 + kk + g * 8];
        bf16x8 b0 = *(const bf16x8*)&sB[(q0 + l16) * LK2 + kk + g * 8];
        bf16x8 b1 = *(const bf16x8*)&sB[(q0 + 16 + l16) * LK2 + kk + g * 8];
        acc00 = __builtin_amdgcn_mfma_f32_16x16x32_bf16(a0, b0, acc00, 0, 0, 0);
        acc01 = __builtin_amdgcn_mfma_f32_16x16x32_bf16(a0, b1, acc01, 0, 0, 0);
        acc10 = __builtin_amdgcn_mfma_f32_16x16x32_bf16(a1, b0, acc10, 0, 0, 0);
        acc11 = __builtin_amdgcn_mfma_f32_16x16x32_bf16(a1, b1, acc11, 0, 0, 0);
    }
    int colA = n0 + q0 + l16;
    int colB = colA + 16;
    float bA = bias1[colA], bB = bias1[colB];
#pragma unroll
    for (int r = 0; r < 4; ++r) {
        int rowi = g * 4 + r;
        int giA = i0 + m0 + rowi;
        int giB = giA + 16;
        if (giA < NN) {
            h1b[(size_t)giA * 256 + colA] = f2bf(fmaxf(acc00[r] + bA, 0.f));
            h1b[(size_t)giA * 256 + colB] = f2bf(fmaxf(acc01[r] + bB, 0.f));
        }
        if (giB < NN) {
            h1b[(size_t)giB * 256 + colA] = f2bf(fmaxf(acc10[r] + bA, 0.f));
            h1b[(size_t)giB * 256 + colB] = f2bf(fmaxf(acc11[r] + bB, 0.f));
        }
    }
}

// ------------------------------------------------------- layer-2 MFMA GEMM
// blockIdx.y==0: zn = h1@w2n -> packed bf16 (48 cols, 24 dwords/row)
// blockIdx.y==1: zsb = h1@w2s + bias2 -> fp32 (48 cols/row)
__global__ __launch_bounds__(256) void gemm2_mfma(
    const unsigned short* __restrict__ h1b, const unsigned short* __restrict__ WB2,
    const float* __restrict__ b2n, const float* __restrict__ b2s,
    unsigned* __restrict__ znb, float* __restrict__ zsb)
{
    __shared__ unsigned short sA[64 * LK2];
    __shared__ unsigned short sB[48 * LK2];
    const int tid = threadIdx.x;
    const int i0 = blockIdx.x * 64;
    const int n0 = blockIdx.y * 48;
    const int wv = tid >> 6, lane = tid & 63;
    const int g = lane >> 4, l16 = lane & 15;
    const int m0 = wv * 16;
    f32x4 acc[3] = {};

#pragma unroll
    for (int l = 0; l < 8; ++l) {
        int c = tid + l * 256;
        int r = c >> 5, c8 = (c & 31) * 8;
        int gi = i0 + r;
        int4 v = make_int4(0, 0, 0, 0);
        if (gi < NN) v = *(const int4*)&h1b[(size_t)gi * 256 + c8];
        *(int4*)&sA[r * LK2 + c8] = v;
    }
#pragma unroll
    for (int l = 0; l < 6; ++l) {
        int c = tid + l * 256;
        int r = c >> 5, c8 = (c & 31) * 8;
        *(int4*)&sB[r * LK2 + c8] = *(const int4*)&WB2[(size_t)(n0 + r) * 256 + c8];
    }
    __syncthreads();
#pragma unroll
    for (int kk = 0; kk < 256; kk += 32) {
        bf16x8 af = *(const bf16x8*)&sA[(m0 + l16) * LK2 + kk + g * 8];
#pragma unroll
        for (int ni = 0; ni < 3; ++ni) {
            bf16x8 bfv = *(const bf16x8*)&sB[(ni * 16 + l16) * LK2 + kk + g * 8];
            acc[ni] = __builtin_amdgcn_mfma_f32_16x16x32_bf16(af, bfv, acc[ni], 0, 0, 0);
        }
    }
    if (blockIdx.y == 0) {
#pragma unroll
        for (int ni = 0; ni < 3; ++ni) {
#pragma unroll
            for (int r = 0; r < 4; ++r) {
                int gi = i0 + m0 + g * 4 + r;
                float v = acc[ni][r];
                float vp = __shfl_down(v, 1);
                if (((l16 & 1) == 0) && gi < NN)
                    znb[(size_t)gi * 24 + ni * 8 + (l16 >> 1)] =
                        (unsigned)f2bf(v) | ((unsigned)f2bf(vp) << 16);
            }
        }
    } else {
#pragma unroll
        for (int ni = 0; ni < 3; ++ni) {
            int c = ni * 16 + l16;
            float bias = (c < CC) ? (b2n[c] + b2s[c]) : 0.f;
#pragma unroll
            for (int r = 0; r < 4; ++r) {
                int gi = i0 + m0 + g * 4 + r;
                if (gi < NN) zsb[(size_t)gi * 48 + c] = acc[ni][r] + bias;
            }
        }
    }
}

// ----------------------- packed-bf16 gather-aggregate + log_softmax + NLL
// grid-stride: wave per node; lanes 0-23 even edges, 32-55 odd edges.
__global__ __launch_bounds__(256) void loss_kernel(
    const unsigned* __restrict__ znb, const float* __restrict__ zsb,
    const int* __restrict__ rp, const int* __restrict__ csr,
    const float* __restrict__ inv,
    const int* __restrict__ y, const int* __restrict__ mask,
    float* __restrict__ accum)
{
    __shared__ float red[8];
    const int tid = threadIdx.x;
    const int wave = tid >> 6, lane = tid & 63;
    const int half = lane >> 5, hl = lane & 31;
    const bool active = hl < 24;
    const int dw = active ? hl : 0;
    const int W = gridDim.x * 4;
    float num = 0.f, den = 0.f;

    for (int i = blockIdx.x * 4 + wave; i < NN; i += W) {
        int s = rp[i], e = rp[i + 1];
        float alo = 0.f, ahi = 0.f, blo = 0.f, bhi = 0.f;
        float clo = 0.f, chi = 0.f, dlo = 0.f, dhi = 0.f;
        for (int base = s; base < e; base += 64) {
            int cnt = min(64, e - base);
            int myidx = csr[min(base + lane, e - 1)];
            int j = 0;
            for (; j + 8 <= cnt; j += 8) {
                int n0 = __shfl(myidx, j + 0 + half);
                int n1 = __shfl(myidx, j + 2 + half);
                int n2 = __shfl(myidx, j + 4 + half);
                int n3 = __shfl(myidx, j + 6 + half);
                unsigned u0 = znb[(size_t)n0 * 24 + dw];
                unsigned u1 = znb[(size_t)n1 * 24 + dw];
                unsigned u2 = znb[(size_t)n2 * 24 + dw];
                unsigned u3 = znb[(size_t)n3 * 24 + dw];
                if (!active) { u0 = u1 = u2 = u3 = 0u; }
                alo += bflo(u0); ahi += bfhi(u0);
                blo += bflo(u1); bhi += bfhi(u1);
                clo += bflo(u2); chi += bfhi(u2);
                dlo += bflo(u3); dhi += bfhi(u3);
            }
            for (; j < cnt; j += 2) {
                int src = j + half;
                int nn = __shfl(myidx, min(src, cnt - 1));
                unsigned u = znb[(size_t)nn * 24 + dw];
                if (!active || src >= cnt) u = 0u;
                alo += bflo(u); ahi += bfhi(u);
            }
        }
        alo = (alo + blo) + (clo + dlo);
        ahi = (ahi + bhi) + (chi + dhi);
        alo += __shfl_xor(alo, 32);
        ahi += __shfl_xor(ahi, 32);
        float sc = inv[i];
        float llo = -1e30f, lhi = -1e30f;
        if (active) {
            llo = alo * sc + zsb[(size_t)i * 48 + 2 * hl];
            lhi = ahi * sc + zsb[(size_t)i * 48 + 2 * hl + 1];
        }
        if (hl == 23) lhi = -1e30f;      // class 47 invalid
        float mx = fmaxf(llo, lhi);
#pragma unroll
        for (int off = 16; off >= 1; off >>= 1)
            mx = fmaxf(mx, __shfl_xor(mx, off));
        float ex = active ? (__expf(llo - mx) + __expf(lhi - mx)) : 0.f;
        float sm = ex;
#pragma unroll
        for (int off = 16; off >= 1; off >>= 1)
            sm += __shfl_xor(sm, off);
        float lse = mx + __logf(sm);
        int yi = y[i];
        float gl = __shfl(llo, yi >> 1);
        float gh = __shfl(lhi, yi >> 1);
        float ly = (yi & 1) ? gh : gl;
        if (lane == 0 && mask[i]) { num += lse - ly; den += 1.f; }
    }
    if (lane == 0) { red[wave * 2] = num; red[wave * 2 + 1] = den; }
    __syncthreads();
    if (tid == 0) {
        atomicAdd(&accum[0], red[0] + red[2] + red[4] + red[6]);
        atomicAdd(&accum[1], red[1] + red[3] + red[5] + red[7]);
    }
}

__global__ void finalize_kernel(const float* __restrict__ accum, float* __restrict__ out) {
    out[0] = accum[0] / fmaxf(accum[1], 1.0f);
}

// ---------------------------------------------------------------- launch
extern "C" void kernel_launch(void* const* d_in, const int* in_sizes, int n_in,
                              void* d_out, int out_size, void* d_ws, size_t ws_size,
                              hipStream_t stream) {
    const float* x   = (const float*)d_in[0];
    const int*   row = (const int*)d_in[1];
    const int*   col = (const int*)d_in[2];
    const int*   y   = (const int*)d_in[3];
    const int*   msk = (const int*)d_in[4];
    const float* w1n = (const float*)d_in[5];
    const float* b1n = (const float*)d_in[6];
    const float* w1s = (const float*)d_in[7];
    const float* b1s = (const float*)d_in[8];
    const float* w2n = (const float*)d_in[9];
    const float* b2n = (const float*)d_in[10];
    const float* w2s = (const float*)d_in[11];
    const float* b2s = (const float*)d_in[12];
    float* out = (float*)d_out;

    float* ws      = (float*)d_ws;
    float* accum   = ws;                                  // 64 f
    int*   deg     = (int*)(ws + 64);                     // 50048
    int*   row_ptr = deg + 50048;                         // 50048
    int*   cursor  = row_ptr + 50048;                     // 50048
    int*   partial = cursor + 50048;                      // 256
    int*   csr     = partial + 256;                       // 800000
    float* inv     = (float*)(csr + 800000);              // 50048
    unsigned* xb   = (unsigned*)(inv + 50048);            // NN*64
    unsigned* ab   = xb + (size_t)NN * 64;                // NN*128 (=[a|x] bf16)
    unsigned short* h1b = (unsigned short*)(ab + (size_t)NN * 128);  // NN*256 bf16
    unsigned* znb  = (unsigned*)(h1b + (size_t)NN * 256); // NN*24 (48 bf16)
    float* zsb     = (float*)(znb + (size_t)NN * 24);     // NN*48 fp32
    unsigned short* WB1 = (unsigned short*)(zsb + (size_t)NN * 48);  // 256*256
    unsigned short* WB2 = WB1 + 65536;                    // 96*256
    float* bias1   = (float*)(WB2 + 24576);               // 256

    const int NBLK = (NN + 255) / 256;    // 196

    (void)hipMemsetAsync(accum, 0, (64 + 50048) * sizeof(float), stream);  // accum + deg

    deg_kernel<<<(EE + 255) / 256, 256, 0, stream>>>(row, deg);
    scan1<<<NBLK, 256, 0, stream>>>(deg, row_ptr, partial);
    scan2<<<1, 256, 0, stream>>>(partial, NBLK);
    scan3<<<NBLK, 256, 0, stream>>>(deg, row_ptr, partial, cursor, inv);
    fill_kernel<<<(EE + 255) / 256, 256, 0, stream>>>(row, col, cursor, csr);

    convert_x<<<(NN * 64 + 255) / 256, 256, 0, stream>>>(x, xb, ab);
    repack_w<<<(65536 + 24576 + 256 + 255) / 256, 256, 0, stream>>>(
        w1n, w1s, b1n, b1s, w2n, w2s, WB1, WB2, bias1);

    agg1<<<GS_BLOCKS, 256, 0, stream>>>(xb, row_ptr, csr, inv, ab);

    dim3 g1((NN + 63) / 64, 4);
    gemm1_mfma<<<g1, 256, 0, stream>>>((const unsigned short*)ab, WB1, bias1, h1b);

    dim3 g2((NN + 63) / 64, 2);
    gemm2_mfma<<<g2, 256, 0, stream>>>(h1b, WB2, b2n, b2s, znb, zsb);

    loss_kernel<<<GS_BLOCKS, 256, 0, stream>>>(
        znb, zsb, row_ptr, csr, inv, y, msk, accum);

    finalize_kernel<<<1, 1, 0, stream>>>(accum, out);
}

// Round 8
// 342.035 us; speedup vs baseline: 13.0508x; 1.0503x over previous
//
#include <hip/hip_runtime.h>
#include <math.h>

#define NN 50000
#define EE 800000
#define DIN 128
#define HH 256
#define CC 47
#define LK2 264     // LDS row stride in bf16 (256 + 8 pad)
#define ZST 16      // znq dword stride per row (48B data in 64B slot -> 1 line/edge)
#define GS_BLOCKS 2048

typedef short bf16x8 __attribute__((ext_vector_type(8)));
typedef float f32x4 __attribute__((ext_vector_type(4)));
typedef float f32x2 __attribute__((ext_vector_type(2)));

static __device__ __forceinline__ unsigned short f2bf(float f) {
    unsigned u = __float_as_uint(f);
    u = u + 0x7fff + ((u >> 16) & 1);
    return (unsigned short)(u >> 16);
}

// ------------------------------------------------------- exclusive scan (3k)
__global__ __launch_bounds__(256) void scan1(const int* __restrict__ deg,
                                             int* __restrict__ row_ptr,
                                             int* __restrict__ partial) {
    __shared__ int tot[4], pre[4];
    int tid = threadIdx.x, t = blockIdx.x * 256 + tid;
    int lane = tid & 63, wave = tid >> 6;
    int v = (t < NN) ? deg[t] : 0;
    int incl = v;
#pragma unroll
    for (int off = 1; off < 64; off <<= 1) {
        int u = __shfl_up(incl, off);
        if (lane >= off) incl += u;
    }
    if (lane == 63) tot[wave] = incl;
    __syncthreads();
    if (tid == 0) {
        int s = 0;
#pragma unroll
        for (int w = 0; w < 4; ++w) { pre[w] = s; s += tot[w]; }
        partial[blockIdx.x] = s;
    }
    __syncthreads();
    if (t < NN) row_ptr[t] = incl - v + pre[wave];
}

__global__ __launch_bounds__(256) void scan2(int* __restrict__ partial, int nblk) {
    __shared__ int tot[4], pre[4];
    int tid = threadIdx.x;
    int lane = tid & 63, wave = tid >> 6;
    int v = (tid < nblk) ? partial[tid] : 0;
    int incl = v;
#pragma unroll
    for (int off = 1; off < 64; off <<= 1) {
        int u = __shfl_up(incl, off);
        if (lane >= off) incl += u;
    }
    if (lane == 63) tot[wave] = incl;
    __syncthreads();
    if (tid == 0) {
        int s = 0;
#pragma unroll
        for (int w = 0; w < 4; ++w) { pre[w] = s; s += tot[w]; }
    }
    __syncthreads();
    partial[tid] = incl - v + pre[wave];
}

__global__ __launch_bounds__(256) void scan3(const int* __restrict__ deg,
                                             int* __restrict__ row_ptr,
                                             const int* __restrict__ partial,
                                             int* __restrict__ cursor,
                                             float* __restrict__ inv) {
    int t = blockIdx.x * 256 + threadIdx.x;
    if (t < NN) {
        int rp = row_ptr[t] + partial[blockIdx.x];
        row_ptr[t] = rp;
        cursor[t] = rp;
        inv[t] = 1.0f / fmaxf((float)deg[t], 1.0f);
    }
    if (t == 0) row_ptr[NN] = EE;
}

__global__ __launch_bounds__(256) void fill_kernel(const int* __restrict__ row,
                                                   const int* __restrict__ col,
                                                   int* __restrict__ cursor,
                                                   int* __restrict__ csr) {
    int e = blockIdx.x * 256 + threadIdx.x;
    if (e < EE) {
        int r = row[e];
        int pos = atomicAdd(&cursor[r], 1);
        csr[pos] = col[e];
    }
}

// ---------------- fused prep: degree count + x->fp8/bf16 + weight repack
__global__ __launch_bounds__(256) void prep_kernel(
    const float* __restrict__ x, const int* __restrict__ row,
    const float* __restrict__ w1n, const float* __restrict__ w1s,
    const float* __restrict__ b1n, const float* __restrict__ b1s,
    const float* __restrict__ w2n, const float* __restrict__ w2s,
    int* __restrict__ deg, unsigned* __restrict__ xq, unsigned* __restrict__ ab,
    unsigned short* __restrict__ WB1, unsigned short* __restrict__ WB2,
    float* __restrict__ bias1)
{
    int t = blockIdx.x * 256 + threadIdx.x;
    if (t < EE) atomicAdd(&deg[row[t]], 1);
    if (t < NN * 32) {
        int i = t >> 5, c = t & 31;
        float4 v = *(const float4*)&x[(size_t)i * DIN + c * 4];
        int p = __builtin_amdgcn_cvt_pk_fp8_f32(v.x, v.y, 0, false);
        p = __builtin_amdgcn_cvt_pk_fp8_f32(v.z, v.w, p, true);
        xq[(size_t)i * 32 + c] = (unsigned)p;
        ab[(size_t)i * 128 + 64 + 2 * c]     = (unsigned)f2bf(v.x) | ((unsigned)f2bf(v.y) << 16);
        ab[(size_t)i * 128 + 64 + 2 * c + 1] = (unsigned)f2bf(v.z) | ((unsigned)f2bf(v.w) << 16);
    }
    if (t < 65536) {
        int n = t >> 8, k = t & 255;
        float v = (k < 128) ? w1n[k * HH + n] : w1s[(k - 128) * HH + n];
        WB1[n * 256 + k] = f2bf(v);
    } else if (t < 65536 + 24576) {
        int q = t - 65536;
        int n = q >> 8, k = q & 255;
        float v;
        if (n < 48) v = (n < CC) ? w2n[k * CC + n] : 0.f;
        else { int m = n - 48; v = (m < CC) ? w2s[k * CC + m] : 0.f; }
        WB2[n * 256 + k] = f2bf(v);
    } else if (t < 65536 + 24576 + 256) {
        int n = t - 65536 - 24576;
        bias1[n] = b1n[n] + b1s[n];
    }
}

// ----------------------------------------------- layer-1 gather (fp8 x)
// grid-stride: wave per node; half-wave per edge (32 dwords = 128 feats fp8).
__global__ __launch_bounds__(256) void agg1(const unsigned* __restrict__ xq,
                                            const int* __restrict__ rp,
                                            const int* __restrict__ csr,
                                            const float* __restrict__ inv,
                                            unsigned* __restrict__ ab) {
    int wave = threadIdx.x >> 6, lane = threadIdx.x & 63;
    const int h = lane >> 5, hl = lane & 31;
    const int W = gridDim.x * 4;
    for (int i = blockIdx.x * 4 + wave; i < NN; i += W) {
        int s = rp[i], e = rp[i + 1];
        float A0=0,A1=0,A2=0,A3=0, B0=0,B1=0,B2=0,B3=0;
        float C0=0,C1=0,C2=0,C3=0, D0=0,D1=0,D2=0,D3=0;
        for (int base = s; base < e; base += 64) {
            int cnt = min(64, e - base);
            int myidx = csr[min(base + lane, e - 1)];
            int j = 0;
            for (; j + 8 <= cnt; j += 8) {
                int n0 = __shfl(myidx, j + h);
                int n1 = __shfl(myidx, j + 2 + h);
                int n2 = __shfl(myidx, j + 4 + h);
                int n3 = __shfl(myidx, j + 6 + h);
                unsigned u0 = xq[(size_t)n0 * 32 + hl];
                unsigned u1 = xq[(size_t)n1 * 32 + hl];
                unsigned u2 = xq[(size_t)n2 * 32 + hl];
                unsigned u3 = xq[(size_t)n3 * 32 + hl];
                f32x2 l0 = __builtin_amdgcn_cvt_pk_f32_fp8(u0, false);
                f32x2 h0 = __builtin_amdgcn_cvt_pk_f32_fp8(u0, true);
                f32x2 l1 = __builtin_amdgcn_cvt_pk_f32_fp8(u1, false);
                f32x2 h1 = __builtin_amdgcn_cvt_pk_f32_fp8(u1, true);
                f32x2 l2 = __builtin_amdgcn_cvt_pk_f32_fp8(u2, false);
                f32x2 h2 = __builtin_amdgcn_cvt_pk_f32_fp8(u2, true);
                f32x2 l3 = __builtin_amdgcn_cvt_pk_f32_fp8(u3, false);
                f32x2 h3 = __builtin_amdgcn_cvt_pk_f32_fp8(u3, true);
                A0 += l0.x; A1 += l0.y; A2 += h0.x; A3 += h0.y;
                B0 += l1.x; B1 += l1.y; B2 += h1.x; B3 += h1.y;
                C0 += l2.x; C1 += l2.y; C2 += h2.x; C3 += h2.y;
                D0 += l3.x; D1 += l3.y; D2 += h3.x; D3 += h3.y;
            }
            for (; j < cnt; j += 2) {
                int src = j + h;
                int n = __shfl(myidx, min(src, cnt - 1));
                unsigned u = xq[(size_t)n * 32 + hl];
                if (src >= cnt) u = 0u;
                f32x2 lo = __builtin_amdgcn_cvt_pk_f32_fp8(u, false);
                f32x2 hi = __builtin_amdgcn_cvt_pk_f32_fp8(u, true);
                A0 += lo.x; A1 += lo.y; A2 += hi.x; A3 += hi.y;
            }
        }
        float s0 = (A0 + B0) + (C0 + D0);
        float s1 = (A1 + B1) + (C1 + D1);
        float s2 = (A2 + B2) + (C2 + D2);
        float s3 = (A3 + B3) + (C3 + D3);
        s0 += __shfl_xor(s0, 32); s1 += __shfl_xor(s1, 32);
        s2 += __shfl_xor(s2, 32); s3 += __shfl_xor(s3, 32);
        if (h == 0) {
            float sc = inv[i];
            unsigned d0 = (unsigned)f2bf(s0 * sc) | ((unsigned)f2bf(s1 * sc) << 16);
            unsigned d1 = (unsigned)f2bf(s2 * sc) | ((unsigned)f2bf(s3 * sc) << 16);
            *(uint2*)&ab[(size_t)i * 128 + 2 * hl] = make_uint2(d0, d1);
        }
    }
}

// ------------------------------------------------------- layer-1 MFMA GEMM
__global__ __launch_bounds__(256) void gemm1_mfma(
    const unsigned short* __restrict__ AB, const unsigned short* __restrict__ WB1,
    const float* __restrict__ bias1, unsigned short* __restrict__ h1b)
{
    __shared__ unsigned short sA[64 * LK2];
    __shared__ unsigned short sB[64 * LK2];
    const int tid = threadIdx.x;
    const int i0 = blockIdx.x * 64;
    const int n0 = blockIdx.y * 64;
    const int wv = tid >> 6, lane = tid & 63;
    const int g = lane >> 4, l16 = lane & 15;
    const int m0 = (wv >> 1) * 32, q0 = (wv & 1) * 32;

    f32x4 acc00 = {}, acc01 = {}, acc10 = {}, acc11 = {};

#pragma unroll
    for (int l = 0; l < 8; ++l) {
        int c = tid + l * 256;
        int r = c >> 5, c8 = (c & 31) * 8;
        int gi = i0 + r;
        int4 v = make_int4(0, 0, 0, 0);
        if (gi < NN) v = *(const int4*)&AB[(size_t)gi * 256 + c8];
        *(int4*)&sA[r * LK2 + c8] = v;
        int4 w = *(const int4*)&WB1[(size_t)(n0 + r) * 256 + c8];
        *(int4*)&sB[r * LK2 + c8] = w;
    }
    __syncthreads();
#pragma unroll
    for (int kk = 0; kk < 256; kk += 32) {
        bf16x8 a0 = *(const bf16x8*)&sA[(m0 + l16) * LK2 + kk + g * 8];
        bf16x8 a1 = *(const bf16x8*)&sA[(m0 + 16 + l16) * LK2 + kk + g * 8];
        bf16x8 b0 = *(const bf16x8*)&sB[(q0 + l16) * LK2 + kk + g * 8];
        bf16x8 b1 = *(const bf16x8*)&sB[(q0 + 16 + l16) * LK2 + kk + g * 8];
        acc00 = __builtin_amdgcn_mfma_f32_16x16x32_bf16(a0, b0, acc00, 0, 0, 0);
        acc01 = __builtin_amdgcn_mfma_f32_16x16x32_bf16(a0, b1, acc01, 0, 0, 0);
        acc10 = __builtin_amdgcn_mfma_f32_16x16x32_bf16(a1, b0, acc10, 0, 0, 0);
        acc11 = __builtin_amdgcn_mfma_f32_16x16x32_bf16(a1, b1, acc11, 0, 0, 0);
    }
    int colA = n0 + q0 + l16;
    int colB = colA + 16;
    float bA = bias1[colA], bB = bias1[colB];
#pragma unroll
    for (int r = 0; r < 4; ++r) {
        int rowi = g * 4 + r;
        int giA = i0 + m0 + rowi;
        int giB = giA + 16;
        if (giA < NN) {
            h1b[(size_t)giA * 256 + colA] = f2bf(fmaxf(acc00[r] + bA, 0.f));
            h1b[(size_t)giA * 256 + colB] = f2bf(fmaxf(acc01[r] + bB, 0.f));
        }
        if (giB < NN) {
            h1b[(size_t)giB * 256 + colA] = f2bf(fmaxf(acc10[r] + bA, 0.f));
            h1b[(size_t)giB * 256 + colB] = f2bf(fmaxf(acc11[r] + bB, 0.f));
        }
    }
}

// ------------------------------------------------------- layer-2 MFMA GEMM
// blockIdx.y==0: znq = fp8(h1@w2n), 48 cols in 16-dword (64B) slots
// blockIdx.y==1: zsb = h1@w2s + bias2 -> fp32 (48 cols/row)
__global__ __launch_bounds__(256) void gemm2_mfma(
    const unsigned short* __restrict__ h1b, const unsigned short* __restrict__ WB2,
    const float* __restrict__ b2n, const float* __restrict__ b2s,
    unsigned* __restrict__ znq, float* __restrict__ zsb)
{
    __shared__ unsigned short sA[64 * LK2];
    __shared__ unsigned short sB[48 * LK2];
    const int tid = threadIdx.x;
    const int i0 = blockIdx.x * 64;
    const int n0 = blockIdx.y * 48;
    const int wv = tid >> 6, lane = tid & 63;
    const int g = lane >> 4, l16 = lane & 15;
    const int m0 = wv * 16;
    f32x4 acc[3] = {};

#pragma unroll
    for (int l = 0; l < 8; ++l) {
        int c = tid + l * 256;
        int r = c >> 5, c8 = (c & 31) * 8;
        int gi = i0 + r;
        int4 v = make_int4(0, 0, 0, 0);
        if (gi < NN) v = *(const int4*)&h1b[(size_t)gi * 256 + c8];
        *(int4*)&sA[r * LK2 + c8] = v;
    }
#pragma unroll
    for (int l = 0; l < 6; ++l) {
        int c = tid + l * 256;
        int r = c >> 5, c8 = (c & 31) * 8;
        *(int4*)&sB[r * LK2 + c8] = *(const int4*)&WB2[(size_t)(n0 + r) * 256 + c8];
    }
    __syncthreads();
#pragma unroll
    for (int kk = 0; kk < 256; kk += 32) {
        bf16x8 af = *(const bf16x8*)&sA[(m0 + l16) * LK2 + kk + g * 8];
#pragma unroll
        for (int ni = 0; ni < 3; ++ni) {
            bf16x8 bfv = *(const bf16x8*)&sB[(ni * 16 + l16) * LK2 + kk + g * 8];
            acc[ni] = __builtin_amdgcn_mfma_f32_16x16x32_bf16(af, bfv, acc[ni], 0, 0, 0);
        }
    }
    if (blockIdx.y == 0) {
#pragma unroll
        for (int ni = 0; ni < 3; ++ni) {
#pragma unroll
            for (int r = 0; r < 4; ++r) {
                int gi = i0 + m0 + g * 4 + r;
                float v0 = acc[ni][r];
                float v1 = __shfl_down(v0, 1);
                float v2 = __shfl_down(v0, 2);
                float v3 = __shfl_down(v0, 3);
                if (((l16 & 3) == 0) && gi < NN) {
                    int p = __builtin_amdgcn_cvt_pk_fp8_f32(v0, v1, 0, false);
                    p = __builtin_amdgcn_cvt_pk_fp8_f32(v2, v3, p, true);
                    znq[(size_t)gi * ZST + ni * 4 + (l16 >> 2)] = (unsigned)p;
                }
            }
        }
    } else {
#pragma unroll
        for (int ni = 0; ni < 3; ++ni) {
            int c = ni * 16 + l16;
            float bias = (c < CC) ? (b2n[c] + b2s[c]) : 0.f;
#pragma unroll
            for (int r = 0; r < 4; ++r) {
                int gi = i0 + m0 + g * 4 + r;
                if (gi < NN) zsb[(size_t)gi * 48 + c] = acc[ni][r] + bias;
            }
        }
    }
}

// ----------------------- fp8 gather-aggregate + log_softmax + NLL + mean
// grid-stride: wave per node; quarter-wave per edge (12 dwords = 48 classes).
__global__ __launch_bounds__(256) void loss_kernel(
    const unsigned* __restrict__ znq, const float* __restrict__ zsb,
    const int* __restrict__ rp, const int* __restrict__ csr,
    const float* __restrict__ inv,
    const int* __restrict__ y, const int* __restrict__ mask,
    float* __restrict__ accum)
{
    __shared__ float red[8];
    const int tid = threadIdx.x;
    const int wave = tid >> 6, lane = tid & 63;
    const int q = lane >> 4, ql = lane & 15;
    const bool act = ql < 12;
    const int dw = act ? ql : 0;
    const int W = gridDim.x * 4;
    float num = 0.f, den = 0.f;

    for (int i = blockIdx.x * 4 + wave; i < NN; i += W) {
        int s = rp[i], e = rp[i + 1];
        float A0=0,A1=0,A2=0,A3=0, B0=0,B1=0,B2=0,B3=0;
        float C0=0,C1=0,C2=0,C3=0, D0=0,D1=0,D2=0,D3=0;
        for (int base = s; base < e; base += 64) {
            int cnt = min(64, e - base);
            int myidx = csr[min(base + lane, e - 1)];
            int j = 0;
            for (; j + 16 <= cnt; j += 16) {
                int n0 = __shfl(myidx, j + q);
                int n1 = __shfl(myidx, j + 4 + q);
                int n2 = __shfl(myidx, j + 8 + q);
                int n3 = __shfl(myidx, j + 12 + q);
                unsigned u0 = znq[(size_t)n0 * ZST + dw];
                unsigned u1 = znq[(size_t)n1 * ZST + dw];
                unsigned u2 = znq[(size_t)n2 * ZST + dw];
                unsigned u3 = znq[(size_t)n3 * ZST + dw];
                if (!act) { u0 = u1 = u2 = u3 = 0u; }
                f32x2 l0 = __builtin_amdgcn_cvt_pk_f32_fp8(u0, false);
                f32x2 h0 = __builtin_amdgcn_cvt_pk_f32_fp8(u0, true);
                f32x2 l1 = __builtin_amdgcn_cvt_pk_f32_fp8(u1, false);
                f32x2 h1 = __builtin_amdgcn_cvt_pk_f32_fp8(u1, true);
                f32x2 l2 = __builtin_amdgcn_cvt_pk_f32_fp8(u2, false);
                f32x2 h2 = __builtin_amdgcn_cvt_pk_f32_fp8(u2, true);
                f32x2 l3 = __builtin_amdgcn_cvt_pk_f32_fp8(u3, false);
                f32x2 h3 = __builtin_amdgcn_cvt_pk_f32_fp8(u3, true);
                A0 += l0.x; A1 += l0.y; A2 += h0.x; A3 += h0.y;
                B0 += l1.x; B1 += l1.y; B2 += h1.x; B3 += h1.y;
                C0 += l2.x; C1 += l2.y; C2 += h2.x; C3 += h2.y;
                D0 += l3.x; D1 += l3.y; D2 += h3.x; D3 += h3.y;
            }
            for (; j < cnt; j += 4) {
                int src = j + q;
                int n = __shfl(myidx, min(src, cnt - 1));
                unsigned u = znq[(size_t)n * ZST + dw];
                if (!act || src >= cnt) u = 0u;
                f32x2 lo = __builtin_amdgcn_cvt_pk_f32_fp8(u, false);
                f32x2 hi = __builtin_amdgcn_cvt_pk_f32_fp8(u, true);
                A0 += lo.x; A1 += lo.y; A2 += hi.x; A3 += hi.y;
            }
        }
        float s0 = (A0 + B0) + (C0 + D0);
        float s1 = (A1 + B1) + (C1 + D1);
        float s2 = (A2 + B2) + (C2 + D2);
        float s3 = (A3 + B3) + (C3 + D3);
        s0 += __shfl_xor(s0, 16); s0 += __shfl_xor(s0, 32);
        s1 += __shfl_xor(s1, 16); s1 += __shfl_xor(s1, 32);
        s2 += __shfl_xor(s2, 16); s2 += __shfl_xor(s2, 32);
        s3 += __shfl_xor(s3, 16); s3 += __shfl_xor(s3, 32);

        float sc = inv[i];
        float g0 = -1e30f, g1 = -1e30f, g2 = -1e30f, g3 = -1e30f;
        if (act) {
            float4 zs = *(const float4*)&zsb[(size_t)i * 48 + 4 * dw];
            g0 = s0 * sc + zs.x;
            g1 = s1 * sc + zs.y;
            g2 = s2 * sc + zs.z;
            g3 = s3 * sc + zs.w;
        }
        if (ql == 11) g3 = -1e30f;   // class 47 invalid
        float mx = fmaxf(fmaxf(g0, g1), fmaxf(g2, g3));
#pragma unroll
        for (int off = 8; off >= 1; off >>= 1)
            mx = fmaxf(mx, __shfl_xor(mx, off));
        float sm = act ? (__expf(g0 - mx) + __expf(g1 - mx) +
                          __expf(g2 - mx) + __expf(g3 - mx)) : 0.f;
#pragma unroll
        for (int off = 8; off >= 1; off >>= 1)
            sm += __shfl_xor(sm, off);
        float lse = mx + __logf(sm);
        int yi = y[i];
        int slot = yi & 3;
        float chosen = (slot == 0) ? g0 : ((slot == 1) ? g1 : ((slot == 2) ? g2 : g3));
        float ly = __shfl(chosen, yi >> 2);
        if (lane == 0 && mask[i]) { num += lse - ly; den += 1.f; }
    }
    if (lane == 0) { red[wave * 2] = num; red[wave * 2 + 1] = den; }
    __syncthreads();
    if (tid == 0) {
        atomicAdd(&accum[0], red[0] + red[2] + red[4] + red[6]);
        atomicAdd(&accum[1], red[1] + red[3] + red[5] + red[7]);
    }
}

__global__ void finalize_kernel(const float* __restrict__ accum, float* __restrict__ out) {
    out[0] = accum[0] / fmaxf(accum[1], 1.0f);
}

// ---------------------------------------------------------------- launch
extern "C" void kernel_launch(void* const* d_in, const int* in_sizes, int n_in,
                              void* d_out, int out_size, void* d_ws, size_t ws_size,
                              hipStream_t stream) {
    const float* x   = (const float*)d_in[0];
    const int*   row = (const int*)d_in[1];
    const int*   col = (const int*)d_in[2];
    const int*   y   = (const int*)d_in[3];
    const int*   msk = (const int*)d_in[4];
    const float* w1n = (const float*)d_in[5];
    const float* b1n = (const float*)d_in[6];
    const float* w1s = (const float*)d_in[7];
    const float* b1s = (const float*)d_in[8];
    const float* w2n = (const float*)d_in[9];
    const float* b2n = (const float*)d_in[10];
    const float* w2s = (const float*)d_in[11];
    const float* b2s = (const float*)d_in[12];
    float* out = (float*)d_out;

    float* ws      = (float*)d_ws;
    float* accum   = ws;                                  // 64 f
    int*   deg     = (int*)(ws + 64);                     // 50048
    int*   row_ptr = deg + 50048;                         // 50048
    int*   cursor  = row_ptr + 50048;                     // 50048
    int*   partial = cursor + 50048;                      // 256
    int*   csr     = partial + 256;                       // 800000
    float* inv     = (float*)(csr + 800000);              // 50048
    unsigned* xq   = (unsigned*)(inv + 50048);            // NN*32 (fp8 x)
    unsigned* ab   = xq + (size_t)NN * 32;                // NN*128 dwords ([a|x] bf16)
    unsigned short* h1b = (unsigned short*)(ab + (size_t)NN * 128);  // NN*256 bf16
    unsigned* znq  = (unsigned*)(h1b + (size_t)NN * 256); // NN*16 (fp8 zn, 64B slots)
    float* zsb     = (float*)(znq + (size_t)NN * ZST);    // NN*48 fp32
    unsigned short* WB1 = (unsigned short*)(zsb + (size_t)NN * 48);  // 256*256
    unsigned short* WB2 = WB1 + 65536;                    // 96*256
    float* bias1   = (float*)(WB2 + 24576);               // 256

    const int NBLK = (NN + 255) / 256;    // 196

    (void)hipMemsetAsync(accum, 0, (64 + 50048) * sizeof(float), stream);  // accum + deg

    prep_kernel<<<(NN * 32 + 255) / 256, 256, 0, stream>>>(
        x, row, w1n, w1s, b1n, b1s, w2n, w2s, deg, xq, ab, WB1, WB2, bias1);

    scan1<<<NBLK, 256, 0, stream>>>(deg, row_ptr, partial);
    scan2<<<1, 256, 0, stream>>>(partial, NBLK);
    scan3<<<NBLK, 256, 0, stream>>>(deg, row_ptr, partial, cursor, inv);
    fill_kernel<<<(EE + 255) / 256, 256, 0, stream>>>(row, col, cursor, csr);

    agg1<<<GS_BLOCKS, 256, 0, stream>>>(xq, row_ptr, csr, inv, ab);

    dim3 g1((NN + 63) / 64, 4);
    gemm1_mfma<<<g1, 256, 0, stream>>>((const unsigned short*)ab, WB1, bias1, h1b);

    dim3 g2((NN + 63) / 64, 2);
    gemm2_mfma<<<g2, 256, 0, stream>>>(h1b, WB2, b2n, b2s, znq, zsb);

    loss_kernel<<<GS_BLOCKS, 256, 0, stream>>>(
        znq, zsb, row_ptr, csr, inv, y, msk, accum);

    finalize_kernel<<<1, 1, 0, stream>>>(accum, out);
}

// Round 9
// 329.000 us; speedup vs baseline: 13.5679x; 1.0396x over previous
//
#include <hip/hip_runtime.h>
#include <math.h>

#define NN 50000
#define EE 800000
#define DIN 128
#define HH 256
#define CC 47
#define LK2 264     // LDS row stride in bf16 (256 + 8 pad)
#define GS_BLOCKS 2048

typedef short bf16x8 __attribute__((ext_vector_type(8)));
typedef float f32x4 __attribute__((ext_vector_type(4)));
typedef float f32x2 __attribute__((ext_vector_type(2)));

static __device__ __forceinline__ unsigned short f2bf(float f) {
    unsigned u = __float_as_uint(f);
    u = u + 0x7fff + ((u >> 16) & 1);
    return (unsigned short)(u >> 16);
}
static __device__ __forceinline__ float bflo(unsigned u) { return __uint_as_float(u << 16); }
static __device__ __forceinline__ float bfhi(unsigned u) { return __uint_as_float(u & 0xffff0000u); }

// ------------------------------------------------------- exclusive scan (3k)
__global__ __launch_bounds__(256) void scan1(const int* __restrict__ deg,
                                             int* __restrict__ row_ptr,
                                             int* __restrict__ partial) {
    __shared__ int tot[4], pre[4];
    int tid = threadIdx.x, t = blockIdx.x * 256 + tid;
    int lane = tid & 63, wave = tid >> 6;
    int v = (t < NN) ? deg[t] : 0;
    int incl = v;
#pragma unroll
    for (int off = 1; off < 64; off <<= 1) {
        int u = __shfl_up(incl, off);
        if (lane >= off) incl += u;
    }
    if (lane == 63) tot[wave] = incl;
    __syncthreads();
    if (tid == 0) {
        int s = 0;
#pragma unroll
        for (int w = 0; w < 4; ++w) { pre[w] = s; s += tot[w]; }
        partial[blockIdx.x] = s;
    }
    __syncthreads();
    if (t < NN) row_ptr[t] = incl - v + pre[wave];
}

__global__ __launch_bounds__(256) void scan2(int* __restrict__ partial, int nblk) {
    __shared__ int tot[4], pre[4];
    int tid = threadIdx.x;
    int lane = tid & 63, wave = tid >> 6;
    int v = (tid < nblk) ? partial[tid] : 0;
    int incl = v;
#pragma unroll
    for (int off = 1; off < 64; off <<= 1) {
        int u = __shfl_up(incl, off);
        if (lane >= off) incl += u;
    }
    if (lane == 63) tot[wave] = incl;
    __syncthreads();
    if (tid == 0) {
        int s = 0;
#pragma unroll
        for (int w = 0; w < 4; ++w) { pre[w] = s; s += tot[w]; }
    }
    __syncthreads();
    partial[tid] = incl - v + pre[wave];
}

__global__ __launch_bounds__(256) void scan3(const int* __restrict__ deg,
                                             int* __restrict__ row_ptr,
                                             const int* __restrict__ partial,
                                             int* __restrict__ cursor,
                                             float* __restrict__ inv) {
    int t = blockIdx.x * 256 + threadIdx.x;
    if (t < NN) {
        int rp = row_ptr[t] + partial[blockIdx.x];
        row_ptr[t] = rp;
        cursor[t] = rp;
        inv[t] = 1.0f / fmaxf((float)deg[t], 1.0f);
    }
    if (t == 0) row_ptr[NN] = EE;
}

__global__ __launch_bounds__(256) void fill_kernel(const int* __restrict__ row,
                                                   const int* __restrict__ col,
                                                   int* __restrict__ cursor,
                                                   int* __restrict__ csr) {
    int e = blockIdx.x * 256 + threadIdx.x;
    if (e < EE) {
        int r = row[e];
        int pos = atomicAdd(&cursor[r], 1);
        csr[pos] = col[e];
    }
}

// -- fused prep: degree + x->fp8/bf16 + weight repack + masked-node compaction
__global__ __launch_bounds__(256) void prep_kernel(
    const float* __restrict__ x, const int* __restrict__ row,
    const int* __restrict__ msk,
    const float* __restrict__ w1n, const float* __restrict__ w1s,
    const float* __restrict__ b1n, const float* __restrict__ b1s,
    const float* __restrict__ w2n, const float* __restrict__ w2s,
    int* __restrict__ deg, unsigned* __restrict__ xq, unsigned* __restrict__ ab,
    unsigned short* __restrict__ WB1, unsigned short* __restrict__ WB2,
    float* __restrict__ bias1, int* __restrict__ mcount, int* __restrict__ mlist)
{
    int t = blockIdx.x * 256 + threadIdx.x;
    if (t < EE) atomicAdd(&deg[row[t]], 1);
    if (t < NN && msk[t]) {
        int p = atomicAdd(mcount, 1);
        mlist[p] = t;
    }
    if (t < NN * 32) {
        int i = t >> 5, c = t & 31;
        float4 v = *(const float4*)&x[(size_t)i * DIN + c * 4];
        int p = __builtin_amdgcn_cvt_pk_fp8_f32(v.x, v.y, 0, false);
        p = __builtin_amdgcn_cvt_pk_fp8_f32(v.z, v.w, p, true);
        xq[(size_t)i * 32 + c] = (unsigned)p;
        ab[(size_t)i * 128 + 64 + 2 * c]     = (unsigned)f2bf(v.x) | ((unsigned)f2bf(v.y) << 16);
        ab[(size_t)i * 128 + 64 + 2 * c + 1] = (unsigned)f2bf(v.z) | ((unsigned)f2bf(v.w) << 16);
    }
    if (t < 65536) {
        int n = t >> 8, k = t & 255;
        float v = (k < 128) ? w1n[k * HH + n] : w1s[(k - 128) * HH + n];
        WB1[n * 256 + k] = f2bf(v);
    } else if (t < 65536 + 24576) {
        int q = t - 65536;
        int n = q >> 8, k = q & 255;
        float v;
        if (n < 48) v = (n < CC) ? w2n[k * CC + n] : 0.f;
        else { int m = n - 48; v = (m < CC) ? w2s[k * CC + m] : 0.f; }
        WB2[n * 256 + k] = f2bf(v);
    } else if (t < 65536 + 24576 + 256) {
        int n = t - 65536 - 24576;
        bias1[n] = b1n[n] + b1s[n];
    }
}

// ----------------------------------------------- layer-1 gather (fp8 x)
// grid-stride: wave per node; half-wave per edge; 16-edge unroll (8 loads deep).
__global__ __launch_bounds__(256) void agg1(const unsigned* __restrict__ xq,
                                            const int* __restrict__ rp,
                                            const int* __restrict__ csr,
                                            const float* __restrict__ inv,
                                            unsigned* __restrict__ ab) {
    int wave = threadIdx.x >> 6, lane = threadIdx.x & 63;
    const int h = lane >> 5, hl = lane & 31;
    const int W = gridDim.x * 4;
    for (int i = blockIdx.x * 4 + wave; i < NN; i += W) {
        int s = rp[i], e = rp[i + 1];
        float A0=0,A1=0,A2=0,A3=0, B0=0,B1=0,B2=0,B3=0;
        float C0=0,C1=0,C2=0,C3=0, D0=0,D1=0,D2=0,D3=0;
        for (int base = s; base < e; base += 64) {
            int cnt = min(64, e - base);
            int myidx = csr[min(base + lane, e - 1)];
            int j = 0;
            for (; j + 16 <= cnt; j += 16) {
                int n0 = __shfl(myidx, j + h);
                int n1 = __shfl(myidx, j + 2 + h);
                int n2 = __shfl(myidx, j + 4 + h);
                int n3 = __shfl(myidx, j + 6 + h);
                int n4 = __shfl(myidx, j + 8 + h);
                int n5 = __shfl(myidx, j + 10 + h);
                int n6 = __shfl(myidx, j + 12 + h);
                int n7 = __shfl(myidx, j + 14 + h);
                unsigned u0 = xq[(size_t)n0 * 32 + hl];
                unsigned u1 = xq[(size_t)n1 * 32 + hl];
                unsigned u2 = xq[(size_t)n2 * 32 + hl];
                unsigned u3 = xq[(size_t)n3 * 32 + hl];
                unsigned u4 = xq[(size_t)n4 * 32 + hl];
                unsigned u5 = xq[(size_t)n5 * 32 + hl];
                unsigned u6 = xq[(size_t)n6 * 32 + hl];
                unsigned u7 = xq[(size_t)n7 * 32 + hl];
                f32x2 l0 = __builtin_amdgcn_cvt_pk_f32_fp8(u0, false);
                f32x2 h0 = __builtin_amdgcn_cvt_pk_f32_fp8(u0, true);
                f32x2 l1 = __builtin_amdgcn_cvt_pk_f32_fp8(u1, false);
                f32x2 h1 = __builtin_amdgcn_cvt_pk_f32_fp8(u1, true);
                f32x2 l2 = __builtin_amdgcn_cvt_pk_f32_fp8(u2, false);
                f32x2 h2 = __builtin_amdgcn_cvt_pk_f32_fp8(u2, true);
                f32x2 l3 = __builtin_amdgcn_cvt_pk_f32_fp8(u3, false);
                f32x2 h3 = __builtin_amdgcn_cvt_pk_f32_fp8(u3, true);
                A0 += l0.x; A1 += l0.y; A2 += h0.x; A3 += h0.y;
                B0 += l1.x; B1 += l1.y; B2 += h1.x; B3 += h1.y;
                C0 += l2.x; C1 += l2.y; C2 += h2.x; C3 += h2.y;
                D0 += l3.x; D1 += l3.y; D2 += h3.x; D3 += h3.y;
                f32x2 l4 = __builtin_amdgcn_cvt_pk_f32_fp8(u4, false);
                f32x2 h4 = __builtin_amdgcn_cvt_pk_f32_fp8(u4, true);
                f32x2 l5 = __builtin_amdgcn_cvt_pk_f32_fp8(u5, false);
                f32x2 h5 = __builtin_amdgcn_cvt_pk_f32_fp8(u5, true);
                f32x2 l6 = __builtin_amdgcn_cvt_pk_f32_fp8(u6, false);
                f32x2 h6 = __builtin_amdgcn_cvt_pk_f32_fp8(u6, true);
                f32x2 l7 = __builtin_amdgcn_cvt_pk_f32_fp8(u7, false);
                f32x2 h7 = __builtin_amdgcn_cvt_pk_f32_fp8(u7, true);
                A0 += l4.x; A1 += l4.y; A2 += h4.x; A3 += h4.y;
                B0 += l5.x; B1 += l5.y; B2 += h5.x; B3 += h5.y;
                C0 += l6.x; C1 += l6.y; C2 += h6.x; C3 += h6.y;
                D0 += l7.x; D1 += l7.y; D2 += h7.x; D3 += h7.y;
            }
            for (; j + 8 <= cnt; j += 8) {
                int n0 = __shfl(myidx, j + h);
                int n1 = __shfl(myidx, j + 2 + h);
                int n2 = __shfl(myidx, j + 4 + h);
                int n3 = __shfl(myidx, j + 6 + h);
                unsigned u0 = xq[(size_t)n0 * 32 + hl];
                unsigned u1 = xq[(size_t)n1 * 32 + hl];
                unsigned u2 = xq[(size_t)n2 * 32 + hl];
                unsigned u3 = xq[(size_t)n3 * 32 + hl];
                f32x2 l0 = __builtin_amdgcn_cvt_pk_f32_fp8(u0, false);
                f32x2 h0 = __builtin_amdgcn_cvt_pk_f32_fp8(u0, true);
                f32x2 l1 = __builtin_amdgcn_cvt_pk_f32_fp8(u1, false);
                f32x2 h1 = __builtin_amdgcn_cvt_pk_f32_fp8(u1, true);
                f32x2 l2 = __builtin_amdgcn_cvt_pk_f32_fp8(u2, false);
                f32x2 h2 = __builtin_amdgcn_cvt_pk_f32_fp8(u2, true);
                f32x2 l3 = __builtin_amdgcn_cvt_pk_f32_fp8(u3, false);
                f32x2 h3 = __builtin_amdgcn_cvt_pk_f32_fp8(u3, true);
                A0 += l0.x; A1 += l0.y; A2 += h0.x; A3 += h0.y;
                B0 += l1.x; B1 += l1.y; B2 += h1.x; B3 += h1.y;
                C0 += l2.x; C1 += l2.y; C2 += h2.x; C3 += h2.y;
                D0 += l3.x; D1 += l3.y; D2 += h3.x; D3 += h3.y;
            }
            for (; j < cnt; j += 2) {
                int src = j + h;
                int n = __shfl(myidx, min(src, cnt - 1));
                unsigned u = xq[(size_t)n * 32 + hl];
                if (src >= cnt) u = 0u;
                f32x2 lo = __builtin_amdgcn_cvt_pk_f32_fp8(u, false);
                f32x2 hi = __builtin_amdgcn_cvt_pk_f32_fp8(u, true);
                A0 += lo.x; A1 += lo.y; A2 += hi.x; A3 += hi.y;
            }
        }
        float s0 = (A0 + B0) + (C0 + D0);
        float s1 = (A1 + B1) + (C1 + D1);
        float s2 = (A2 + B2) + (C2 + D2);
        float s3 = (A3 + B3) + (C3 + D3);
        s0 += __shfl_xor(s0, 32); s1 += __shfl_xor(s1, 32);
        s2 += __shfl_xor(s2, 32); s3 += __shfl_xor(s3, 32);
        if (h == 0) {
            float sc = inv[i];
            unsigned d0 = (unsigned)f2bf(s0 * sc) | ((unsigned)f2bf(s1 * sc) << 16);
            unsigned d1 = (unsigned)f2bf(s2 * sc) | ((unsigned)f2bf(s3 * sc) << 16);
            *(uint2*)&ab[(size_t)i * 128 + 2 * hl] = make_uint2(d0, d1);
        }
    }
}

// ------------------------------------------------------- layer-1 MFMA GEMM
__global__ __launch_bounds__(256) void gemm1_mfma(
    const unsigned short* __restrict__ AB, const unsigned short* __restrict__ WB1,
    const float* __restrict__ bias1, unsigned short* __restrict__ h1b)
{
    __shared__ unsigned short sA[64 * LK2];
    __shared__ unsigned short sB[64 * LK2];
    const int tid = threadIdx.x;
    const int i0 = blockIdx.x * 64;
    const int n0 = blockIdx.y * 64;
    const int wv = tid >> 6, lane = tid & 63;
    const int g = lane >> 4, l16 = lane & 15;
    const int m0 = (wv >> 1) * 32, q0 = (wv & 1) * 32;

    f32x4 acc00 = {}, acc01 = {}, acc10 = {}, acc11 = {};

#pragma unroll
    for (int l = 0; l < 8; ++l) {
        int c = tid + l * 256;
        int r = c >> 5, c8 = (c & 31) * 8;
        int gi = i0 + r;
        int4 v = make_int4(0, 0, 0, 0);
        if (gi < NN) v = *(const int4*)&AB[(size_t)gi * 256 + c8];
        *(int4*)&sA[r * LK2 + c8] = v;
        int4 w = *(const int4*)&WB1[(size_t)(n0 + r) * 256 + c8];
        *(int4*)&sB[r * LK2 + c8] = w;
    }
    __syncthreads();
#pragma unroll
    for (int kk = 0; kk < 256; kk += 32) {
        bf16x8 a0 = *(const bf16x8*)&sA[(m0 + l16) * LK2 + kk + g * 8];
        bf16x8 a1 = *(const bf16x8*)&sA[(m0 + 16 + l16) * LK2 + kk + g * 8];
        bf16x8 b0 = *(const bf16x8*)&sB[(q0 + l16) * LK2 + kk + g * 8];
        bf16x8 b1 = *(const bf16x8*)&sB[(q0 + 16 + l16) * LK2 + kk + g * 8];
        acc00 = __builtin_amdgcn_mfma_f32_16x16x32_bf16(a0, b0, acc00, 0, 0, 0);
        acc01 = __builtin_amdgcn_mfma_f32_16x16x32_bf16(a0, b1, acc01, 0, 0, 0);
        acc10 = __builtin_amdgcn_mfma_f32_16x16x32_bf16(a1, b0, acc10, 0, 0, 0);
        acc11 = __builtin_amdgcn_mfma_f32_16x16x32_bf16(a1, b1, acc11, 0, 0, 0);
    }
    int colA = n0 + q0 + l16;
    int colB = colA + 16;
    float bA = bias1[colA], bB = bias1[colB];
#pragma unroll
    for (int r = 0; r < 4; ++r) {
        int rowi = g * 4 + r;
        int giA = i0 + m0 + rowi;
        int giB = giA + 16;
        if (giA < NN) {
            h1b[(size_t)giA * 256 + colA] = f2bf(fmaxf(acc00[r] + bA, 0.f));
            h1b[(size_t)giA * 256 + colB] = f2bf(fmaxf(acc01[r] + bB, 0.f));
        }
        if (giB < NN) {
            h1b[(size_t)giB * 256 + colA] = f2bf(fmaxf(acc10[r] + bA, 0.f));
            h1b[(size_t)giB * 256 + colB] = f2bf(fmaxf(acc11[r] + bB, 0.f));
        }
    }
}

// ------------------------------------------------------- layer-2 MFMA GEMM
// blockIdx.y==0: znb = bf16(h1@w2n), 48 cols packed in 24 dwords/row
// blockIdx.y==1: zsb = h1@w2s + bias2 -> fp32 (48 cols/row)
__global__ __launch_bounds__(256) void gemm2_mfma(
    const unsigned short* __restrict__ h1b, const unsigned short* __restrict__ WB2,
    const float* __restrict__ b2n, const float* __restrict__ b2s,
    unsigned* __restrict__ znb, float* __restrict__ zsb)
{
    __shared__ unsigned short sA[64 * LK2];
    __shared__ unsigned short sB[48 * LK2];
    const int tid = threadIdx.x;
    const int i0 = blockIdx.x * 64;
    const int n0 = blockIdx.y * 48;
    const int wv = tid >> 6, lane = tid & 63;
    const int g = lane >> 4, l16 = lane & 15;
    const int m0 = wv * 16;
    f32x4 acc[3] = {};

#pragma unroll
    for (int l = 0; l < 8; ++l) {
        int c = tid + l * 256;
        int r = c >> 5, c8 = (c & 31) * 8;
        int gi = i0 + r;
        int4 v = make_int4(0, 0, 0, 0);
        if (gi < NN) v = *(const int4*)&h1b[(size_t)gi * 256 + c8];
        *(int4*)&sA[r * LK2 + c8] = v;
    }
#pragma unroll
    for (int l = 0; l < 6; ++l) {
        int c = tid + l * 256;
        int r = c >> 5, c8 = (c & 31) * 8;
        *(int4*)&sB[r * LK2 + c8] = *(const int4*)&WB2[(size_t)(n0 + r) * 256 + c8];
    }
    __syncthreads();
#pragma unroll
    for (int kk = 0; kk < 256; kk += 32) {
        bf16x8 af = *(const bf16x8*)&sA[(m0 + l16) * LK2 + kk + g * 8];
#pragma unroll
        for (int ni = 0; ni < 3; ++ni) {
            bf16x8 bfv = *(const bf16x8*)&sB[(ni * 16 + l16) * LK2 + kk + g * 8];
            acc[ni] = __builtin_amdgcn_mfma_f32_16x16x32_bf16(af, bfv, acc[ni], 0, 0, 0);
        }
    }
    if (blockIdx.y == 0) {
#pragma unroll
        for (int ni = 0; ni < 3; ++ni) {
#pragma unroll
            for (int r = 0; r < 4; ++r) {
                int gi = i0 + m0 + g * 4 + r;
                float v = acc[ni][r];
                float vp = __shfl_down(v, 1);
                if (((l16 & 1) == 0) && gi < NN)
                    znb[(size_t)gi * 24 + ni * 8 + (l16 >> 1)] =
                        (unsigned)f2bf(v) | ((unsigned)f2bf(vp) << 16);
            }
        }
    } else {
#pragma unroll
        for (int ni = 0; ni < 3; ++ni) {
            int c = ni * 16 + l16;
            float bias = (c < CC) ? (b2n[c] + b2s[c]) : 0.f;
#pragma unroll
            for (int r = 0; r < 4; ++r) {
                int gi = i0 + m0 + g * 4 + r;
                if (gi < NN) zsb[(size_t)gi * 48 + c] = acc[ni][r] + bias;
            }
        }
    }
}

// ----------------------- masked-only bf16 gather + log_softmax + NLL + mean
// grid-stride over compacted mlist; lanes 0-23 even edges, 32-55 odd edges.
__global__ __launch_bounds__(256) void loss_kernel(
    const unsigned* __restrict__ znb, const float* __restrict__ zsb,
    const int* __restrict__ rp, const int* __restrict__ csr,
    const float* __restrict__ inv,
    const int* __restrict__ y,
    const int* __restrict__ mcount, const int* __restrict__ mlist,
    float* __restrict__ accum)
{
    __shared__ float red[8];
    const int tid = threadIdx.x;
    const int wave = tid >> 6, lane = tid & 63;
    const int half = lane >> 5, hl = lane & 31;
    const bool active = hl < 24;
    const int dw = active ? hl : 0;
    const int W = gridDim.x * 4;
    const int M = mcount[0];
    float num = 0.f, den = 0.f;

    for (int idx = blockIdx.x * 4 + wave; idx < M; idx += W) {
        int i = mlist[idx];
        int s = rp[i], e = rp[i + 1];
        float alo = 0.f, ahi = 0.f, blo = 0.f, bhi = 0.f;
        float clo = 0.f, chi = 0.f, dlo = 0.f, dhi = 0.f;
        for (int base = s; base < e; base += 64) {
            int cnt = min(64, e - base);
            int myidx = csr[min(base + lane, e - 1)];
            int j = 0;
            for (; j + 8 <= cnt; j += 8) {
                int n0 = __shfl(myidx, j + 0 + half);
                int n1 = __shfl(myidx, j + 2 + half);
                int n2 = __shfl(myidx, j + 4 + half);
                int n3 = __shfl(myidx, j + 6 + half);
                unsigned u0 = znb[(size_t)n0 * 24 + dw];
                unsigned u1 = znb[(size_t)n1 * 24 + dw];
                unsigned u2 = znb[(size_t)n2 * 24 + dw];
                unsigned u3 = znb[(size_t)n3 * 24 + dw];
                if (!active) { u0 = u1 = u2 = u3 = 0u; }
                alo += bflo(u0); ahi += bfhi(u0);
                blo += bflo(u1); bhi += bfhi(u1);
                clo += bflo(u2); chi += bfhi(u2);
                dlo += bflo(u3); dhi += bfhi(u3);
            }
            for (; j < cnt; j += 2) {
                int src = j + half;
                int nn = __shfl(myidx, min(src, cnt - 1));
                unsigned u = znb[(size_t)nn * 24 + dw];
                if (!active || src >= cnt) u = 0u;
                alo += bflo(u); ahi += bfhi(u);
            }
        }
        alo = (alo + blo) + (clo + dlo);
        ahi = (ahi + bhi) + (chi + dhi);
        alo += __shfl_xor(alo, 32);
        ahi += __shfl_xor(ahi, 32);
        float sc = inv[i];
        float llo = -1e30f, lhi = -1e30f;
        if (active) {
            llo = alo * sc + zsb[(size_t)i * 48 + 2 * hl];
            lhi = ahi * sc + zsb[(size_t)i * 48 + 2 * hl + 1];
        }
        if (hl == 23) lhi = -1e30f;      // class 47 invalid
        float mx = fmaxf(llo, lhi);
#pragma unroll
        for (int off = 16; off >= 1; off >>= 1)
            mx = fmaxf(mx, __shfl_xor(mx, off));
        float ex = active ? (__expf(llo - mx) + __expf(lhi - mx)) : 0.f;
        float sm = ex;
#pragma unroll
        for (int off = 16; off >= 1; off >>= 1)
            sm += __shfl_xor(sm, off);
        float lse = mx + __logf(sm);
        int yi = y[i];
        float gl = __shfl(llo, yi >> 1);
        float gh = __shfl(lhi, yi >> 1);
        float ly = (yi & 1) ? gh : gl;
        if (lane == 0) { num += lse - ly; den += 1.f; }
    }
    if (lane == 0) { red[wave * 2] = num; red[wave * 2 + 1] = den; }
    __syncthreads();
    if (tid == 0) {
        atomicAdd(&accum[0], red[0] + red[2] + red[4] + red[6]);
        atomicAdd(&accum[1], red[1] + red[3] + red[5] + red[7]);
    }
}

__global__ void finalize_kernel(const float* __restrict__ accum, float* __restrict__ out) {
    out[0] = accum[0] / fmaxf(accum[1], 1.0f);
}

// ---------------------------------------------------------------- launch
extern "C" void kernel_launch(void* const* d_in, const int* in_sizes, int n_in,
                              void* d_out, int out_size, void* d_ws, size_t ws_size,
                              hipStream_t stream) {
    const float* x   = (const float*)d_in[0];
    const int*   row = (const int*)d_in[1];
    const int*   col = (const int*)d_in[2];
    const int*   y   = (const int*)d_in[3];
    const int*   msk = (const int*)d_in[4];
    const float* w1n = (const float*)d_in[5];
    const float* b1n = (const float*)d_in[6];
    const float* w1s = (const float*)d_in[7];
    const float* b1s = (const float*)d_in[8];
    const float* w2n = (const float*)d_in[9];
    const float* b2n = (const float*)d_in[10];
    const float* w2s = (const float*)d_in[11];
    const float* b2s = (const float*)d_in[12];
    float* out = (float*)d_out;

    float* ws      = (float*)d_ws;
    float* accum   = ws;                                  // 64 f (mcount at +32)
    int*   mcount  = (int*)(ws + 32);
    int*   deg     = (int*)(ws + 64);                     // 50048
    int*   row_ptr = deg + 50048;                         // 50048
    int*   cursor  = row_ptr + 50048;                     // 50048
    int*   partial = cursor + 50048;                      // 256
    int*   csr     = partial + 256;                       // 800000
    float* inv     = (float*)(csr + 800000);              // 50048
    unsigned* xq   = (unsigned*)(inv + 50048);            // NN*32 (fp8 x)
    unsigned* ab   = xq + (size_t)NN * 32;                // NN*128 dwords ([a|x] bf16)
    unsigned short* h1b = (unsigned short*)(ab + (size_t)NN * 128);  // NN*256 bf16
    unsigned* znb  = (unsigned*)(h1b + (size_t)NN * 256); // NN*24 (48 bf16)
    float* zsb     = (float*)(znb + (size_t)NN * 24);     // NN*48 fp32
    unsigned short* WB1 = (unsigned short*)(zsb + (size_t)NN * 48);  // 256*256
    unsigned short* WB2 = WB1 + 65536;                    // 96*256
    float* bias1   = (float*)(WB2 + 24576);               // 256
    int*   mlist   = (int*)(bias1 + 256);                 // 50048

    const int NBLK = (NN + 255) / 256;    // 196

    (void)hipMemsetAsync(accum, 0, (64 + 50048) * sizeof(float), stream);  // accum+mcount+deg

    prep_kernel<<<(NN * 32 + 255) / 256, 256, 0, stream>>>(
        x, row, msk, w1n, w1s, b1n, b1s, w2n, w2s,
        deg, xq, ab, WB1, WB2, bias1, mcount, mlist);

    scan1<<<NBLK, 256, 0, stream>>>(deg, row_ptr, partial);
    scan2<<<1, 256, 0, stream>>>(partial, NBLK);
    scan3<<<NBLK, 256, 0, stream>>>(deg, row_ptr, partial, cursor, inv);
    fill_kernel<<<(EE + 255) / 256, 256, 0, stream>>>(row, col, cursor, csr);

    agg1<<<GS_BLOCKS, 256, 0, stream>>>(xq, row_ptr, csr, inv, ab);

    dim3 g1((NN + 63) / 64, 4);
    gemm1_mfma<<<g1, 256, 0, stream>>>((const unsigned short*)ab, WB1, bias1, h1b);

    dim3 g2((NN + 63) / 64, 2);
    gemm2_mfma<<<g2, 256, 0, stream>>>(h1b, WB2, b2n, b2s, znb, zsb);

    loss_kernel<<<GS_BLOCKS, 256, 0, stream>>>(
        znb, zsb, row_ptr, csr, inv, y, mcount, mlist, accum);

    finalize_kernel<<<1, 1, 0, stream>>>(accum, out);
}

// Round 10
// 319.541 us; speedup vs baseline: 13.9695x; 1.0296x over previous
//
#include <hip/hip_runtime.h>
#include <math.h>

#define NN 50000
#define EE 800000
#define DIN 128
#define HH 256
#define CC 47
#define LK2 264     // LDS row stride in bf16 (256 + 8 pad)
#define GS_BLOCKS 2048

typedef short bf16x8 __attribute__((ext_vector_type(8)));
typedef float f32x4 __attribute__((ext_vector_type(4)));
typedef float f32x2 __attribute__((ext_vector_type(2)));

static __device__ __forceinline__ unsigned short f2bf(float f) {
    unsigned u = __float_as_uint(f);
    u = u + 0x7fff + ((u >> 16) & 1);
    return (unsigned short)(u >> 16);
}
static __device__ __forceinline__ float bflo(unsigned u) { return __uint_as_float(u << 16); }
static __device__ __forceinline__ float bfhi(unsigned u) { return __uint_as_float(u & 0xffff0000u); }

// ------------------------------------------------------- exclusive scan (3k)
__global__ __launch_bounds__(256) void scan1(const int* __restrict__ deg,
                                             int* __restrict__ row_ptr,
                                             int* __restrict__ partial) {
    __shared__ int tot[4], pre[4];
    int tid = threadIdx.x, t = blockIdx.x * 256 + tid;
    int lane = tid & 63, wave = tid >> 6;
    int v = (t < NN) ? deg[t] : 0;
    int incl = v;
#pragma unroll
    for (int off = 1; off < 64; off <<= 1) {
        int u = __shfl_up(incl, off);
        if (lane >= off) incl += u;
    }
    if (lane == 63) tot[wave] = incl;
    __syncthreads();
    if (tid == 0) {
        int s = 0;
#pragma unroll
        for (int w = 0; w < 4; ++w) { pre[w] = s; s += tot[w]; }
        partial[blockIdx.x] = s;
    }
    __syncthreads();
    if (t < NN) row_ptr[t] = incl - v + pre[wave];
}

__global__ __launch_bounds__(256) void scan2(int* __restrict__ partial, int nblk) {
    __shared__ int tot[4], pre[4];
    int tid = threadIdx.x;
    int lane = tid & 63, wave = tid >> 6;
    int v = (tid < nblk) ? partial[tid] : 0;
    int incl = v;
#pragma unroll
    for (int off = 1; off < 64; off <<= 1) {
        int u = __shfl_up(incl, off);
        if (lane >= off) incl += u;
    }
    if (lane == 63) tot[wave] = incl;
    __syncthreads();
    if (tid == 0) {
        int s = 0;
#pragma unroll
        for (int w = 0; w < 4; ++w) { pre[w] = s; s += tot[w]; }
    }
    __syncthreads();
    partial[tid] = incl - v + pre[wave];
}

__global__ __launch_bounds__(256) void scan3(const int* __restrict__ deg,
                                             int* __restrict__ row_ptr,
                                             const int* __restrict__ partial,
                                             int* __restrict__ cursor,
                                             float* __restrict__ inv) {
    int t = blockIdx.x * 256 + threadIdx.x;
    if (t < NN) {
        int rp = row_ptr[t] + partial[blockIdx.x];
        row_ptr[t] = rp;
        cursor[t] = rp;
        inv[t] = 1.0f / fmaxf((float)deg[t], 1.0f);
    }
    if (t == 0) row_ptr[NN] = EE;
}

__global__ __launch_bounds__(256) void fill_kernel(const int* __restrict__ row,
                                                   const int* __restrict__ col,
                                                   int* __restrict__ cursor,
                                                   int* __restrict__ csr) {
    int e = blockIdx.x * 256 + threadIdx.x;
    if (e < EE) {
        int r = row[e];
        int pos = atomicAdd(&cursor[r], 1);
        csr[pos] = col[e];
    }
}

// -- fused prep: degree + x->fp8/bf16 + weight repack + masked-node compaction
__global__ __launch_bounds__(256) void prep_kernel(
    const float* __restrict__ x, const int* __restrict__ row,
    const int* __restrict__ msk,
    const float* __restrict__ w1n, const float* __restrict__ w1s,
    const float* __restrict__ b1n, const float* __restrict__ b1s,
    const float* __restrict__ w2n, const float* __restrict__ w2s,
    int* __restrict__ deg, unsigned* __restrict__ xq, unsigned* __restrict__ ab,
    unsigned short* __restrict__ WB1, unsigned short* __restrict__ WB2,
    float* __restrict__ bias1, int* __restrict__ mcount, int* __restrict__ mlist)
{
    int t = blockIdx.x * 256 + threadIdx.x;
    if (t < EE) atomicAdd(&deg[row[t]], 1);
    if (t < NN && msk[t]) {
        int p = atomicAdd(mcount, 1);
        mlist[p] = t;
    }
    if (t < NN * 32) {
        int i = t >> 5, c = t & 31;
        float4 v = *(const float4*)&x[(size_t)i * DIN + c * 4];
        int p = __builtin_amdgcn_cvt_pk_fp8_f32(v.x, v.y, 0, false);
        p = __builtin_amdgcn_cvt_pk_fp8_f32(v.z, v.w, p, true);
        xq[(size_t)i * 32 + c] = (unsigned)p;
        ab[(size_t)i * 128 + 64 + 2 * c]     = (unsigned)f2bf(v.x) | ((unsigned)f2bf(v.y) << 16);
        ab[(size_t)i * 128 + 64 + 2 * c + 1] = (unsigned)f2bf(v.z) | ((unsigned)f2bf(v.w) << 16);
    }
    if (t < 65536) {
        int n = t >> 8, k = t & 255;
        float v = (k < 128) ? w1n[k * HH + n] : w1s[(k - 128) * HH + n];
        WB1[n * 256 + k] = f2bf(v);
    } else if (t < 65536 + 24576) {
        int q = t - 65536;
        int n = q >> 8, k = q & 255;
        float v;
        if (n < 48) v = (n < CC) ? w2n[k * CC + n] : 0.f;
        else { int m = n - 48; v = (m < CC) ? w2s[k * CC + m] : 0.f; }
        WB2[n * 256 + k] = f2bf(v);
    } else if (t < 65536 + 24576 + 256) {
        int n = t - 65536 - 24576;
        bias1[n] = b1n[n] + b1s[n];
    }
}

// ----------------------------------------------- layer-1 gather (fp8 x)
// grid-stride: wave per node; half-wave per edge; 16-edge unroll (8 loads deep).
__global__ __launch_bounds__(256) void agg1(const unsigned* __restrict__ xq,
                                            const int* __restrict__ rp,
                                            const int* __restrict__ csr,
                                            const float* __restrict__ inv,
                                            unsigned* __restrict__ ab) {
    int wave = threadIdx.x >> 6, lane = threadIdx.x & 63;
    const int h = lane >> 5, hl = lane & 31;
    const int W = gridDim.x * 4;
    for (int i = blockIdx.x * 4 + wave; i < NN; i += W) {
        int s = rp[i], e = rp[i + 1];
        float A0=0,A1=0,A2=0,A3=0, B0=0,B1=0,B2=0,B3=0;
        float C0=0,C1=0,C2=0,C3=0, D0=0,D1=0,D2=0,D3=0;
        for (int base = s; base < e; base += 64) {
            int cnt = min(64, e - base);
            int myidx = csr[min(base + lane, e - 1)];
            int j = 0;
            for (; j + 16 <= cnt; j += 16) {
                int n0 = __shfl(myidx, j + h);
                int n1 = __shfl(myidx, j + 2 + h);
                int n2 = __shfl(myidx, j + 4 + h);
                int n3 = __shfl(myidx, j + 6 + h);
                int n4 = __shfl(myidx, j + 8 + h);
                int n5 = __shfl(myidx, j + 10 + h);
                int n6 = __shfl(myidx, j + 12 + h);
                int n7 = __shfl(myidx, j + 14 + h);
                unsigned u0 = xq[(size_t)n0 * 32 + hl];
                unsigned u1 = xq[(size_t)n1 * 32 + hl];
                unsigned u2 = xq[(size_t)n2 * 32 + hl];
                unsigned u3 = xq[(size_t)n3 * 32 + hl];
                unsigned u4 = xq[(size_t)n4 * 32 + hl];
                unsigned u5 = xq[(size_t)n5 * 32 + hl];
                unsigned u6 = xq[(size_t)n6 * 32 + hl];
                unsigned u7 = xq[(size_t)n7 * 32 + hl];
                f32x2 l0 = __builtin_amdgcn_cvt_pk_f32_fp8(u0, false);
                f32x2 h0 = __builtin_amdgcn_cvt_pk_f32_fp8(u0, true);
                f32x2 l1 = __builtin_amdgcn_cvt_pk_f32_fp8(u1, false);
                f32x2 h1 = __builtin_amdgcn_cvt_pk_f32_fp8(u1, true);
                f32x2 l2 = __builtin_amdgcn_cvt_pk_f32_fp8(u2, false);
                f32x2 h2 = __builtin_amdgcn_cvt_pk_f32_fp8(u2, true);
                f32x2 l3 = __builtin_amdgcn_cvt_pk_f32_fp8(u3, false);
                f32x2 h3 = __builtin_amdgcn_cvt_pk_f32_fp8(u3, true);
                A0 += l0.x; A1 += l0.y; A2 += h0.x; A3 += h0.y;
                B0 += l1.x; B1 += l1.y; B2 += h1.x; B3 += h1.y;
                C0 += l2.x; C1 += l2.y; C2 += h2.x; C3 += h2.y;
                D0 += l3.x; D1 += l3.y; D2 += h3.x; D3 += h3.y;
                f32x2 l4 = __builtin_amdgcn_cvt_pk_f32_fp8(u4, false);
                f32x2 h4 = __builtin_amdgcn_cvt_pk_f32_fp8(u4, true);
                f32x2 l5 = __builtin_amdgcn_cvt_pk_f32_fp8(u5, false);
                f32x2 h5 = __builtin_amdgcn_cvt_pk_f32_fp8(u5, true);
                f32x2 l6 = __builtin_amdgcn_cvt_pk_f32_fp8(u6, false);
                f32x2 h6 = __builtin_amdgcn_cvt_pk_f32_fp8(u6, true);
                f32x2 l7 = __builtin_amdgcn_cvt_pk_f32_fp8(u7, false);
                f32x2 h7 = __builtin_amdgcn_cvt_pk_f32_fp8(u7, true);
                A0 += l4.x; A1 += l4.y; A2 += h4.x; A3 += h4.y;
                B0 += l5.x; B1 += l5.y; B2 += h5.x; B3 += h5.y;
                C0 += l6.x; C1 += l6.y; C2 += h6.x; C3 += h6.y;
                D0 += l7.x; D1 += l7.y; D2 += h7.x; D3 += h7.y;
            }
            for (; j + 8 <= cnt; j += 8) {
                int n0 = __shfl(myidx, j + h);
                int n1 = __shfl(myidx, j + 2 + h);
                int n2 = __shfl(myidx, j + 4 + h);
                int n3 = __shfl(myidx, j + 6 + h);
                unsigned u0 = xq[(size_t)n0 * 32 + hl];
                unsigned u1 = xq[(size_t)n1 * 32 + hl];
                unsigned u2 = xq[(size_t)n2 * 32 + hl];
                unsigned u3 = xq[(size_t)n3 * 32 + hl];
                f32x2 l0 = __builtin_amdgcn_cvt_pk_f32_fp8(u0, false);
                f32x2 h0 = __builtin_amdgcn_cvt_pk_f32_fp8(u0, true);
                f32x2 l1 = __builtin_amdgcn_cvt_pk_f32_fp8(u1, false);
                f32x2 h1 = __builtin_amdgcn_cvt_pk_f32_fp8(u1, true);
                f32x2 l2 = __builtin_amdgcn_cvt_pk_f32_fp8(u2, false);
                f32x2 h2 = __builtin_amdgcn_cvt_pk_f32_fp8(u2, true);
                f32x2 l3 = __builtin_amdgcn_cvt_pk_f32_fp8(u3, false);
                f32x2 h3 = __builtin_amdgcn_cvt_pk_f32_fp8(u3, true);
                A0 += l0.x; A1 += l0.y; A2 += h0.x; A3 += h0.y;
                B0 += l1.x; B1 += l1.y; B2 += h1.x; B3 += h1.y;
                C0 += l2.x; C1 += l2.y; C2 += h2.x; C3 += h2.y;
                D0 += l3.x; D1 += l3.y; D2 += h3.x; D3 += h3.y;
            }
            for (; j < cnt; j += 2) {
                int src = j + h;
                int n = __shfl(myidx, min(src, cnt - 1));
                unsigned u = xq[(size_t)n * 32 + hl];
                if (src >= cnt) u = 0u;
                f32x2 lo = __builtin_amdgcn_cvt_pk_f32_fp8(u, false);
                f32x2 hi = __builtin_amdgcn_cvt_pk_f32_fp8(u, true);
                A0 += lo.x; A1 += lo.y; A2 += hi.x; A3 += hi.y;
            }
        }
        float s0 = (A0 + B0) + (C0 + D0);
        float s1 = (A1 + B1) + (C1 + D1);
        float s2 = (A2 + B2) + (C2 + D2);
        float s3 = (A3 + B3) + (C3 + D3);
        s0 += __shfl_xor(s0, 32); s1 += __shfl_xor(s1, 32);
        s2 += __shfl_xor(s2, 32); s3 += __shfl_xor(s3, 32);
        if (h == 0) {
            float sc = inv[i];
            unsigned d0 = (unsigned)f2bf(s0 * sc) | ((unsigned)f2bf(s1 * sc) << 16);
            unsigned d1 = (unsigned)f2bf(s2 * sc) | ((unsigned)f2bf(s3 * sc) << 16);
            *(uint2*)&ab[(size_t)i * 128 + 2 * hl] = make_uint2(d0, d1);
        }
    }
}

// ------------------------------------------------------- layer-1 MFMA GEMM
__global__ __launch_bounds__(256) void gemm1_mfma(
    const unsigned short* __restrict__ AB, const unsigned short* __restrict__ WB1,
    const float* __restrict__ bias1, unsigned short* __restrict__ h1b)
{
    __shared__ unsigned short sA[64 * LK2];
    __shared__ unsigned short sB[64 * LK2];
    const int tid = threadIdx.x;
    const int i0 = blockIdx.x * 64;
    const int n0 = blockIdx.y * 64;
    const int wv = tid >> 6, lane = tid & 63;
    const int g = lane >> 4, l16 = lane & 15;
    const int m0 = (wv >> 1) * 32, q0 = (wv & 1) * 32;

    f32x4 acc00 = {}, acc01 = {}, acc10 = {}, acc11 = {};

#pragma unroll
    for (int l = 0; l < 8; ++l) {
        int c = tid + l * 256;
        int r = c >> 5, c8 = (c & 31) * 8;
        int gi = i0 + r;
        int4 v = make_int4(0, 0, 0, 0);
        if (gi < NN) v = *(const int4*)&AB[(size_t)gi * 256 + c8];
        *(int4*)&sA[r * LK2 + c8] = v;
        int4 w = *(const int4*)&WB1[(size_t)(n0 + r) * 256 + c8];
        *(int4*)&sB[r * LK2 + c8] = w;
    }
    __syncthreads();
#pragma unroll
    for (int kk = 0; kk < 256; kk += 32) {
        bf16x8 a0 = *(const bf16x8*)&sA[(m0 + l16) * LK2 + kk + g * 8];
        bf16x8 a1 = *(const bf16x8*)&sA[(m0 + 16 + l16) * LK2 + kk + g * 8];
        bf16x8 b0 = *(const bf16x8*)&sB[(q0 + l16) * LK2 + kk + g * 8];
        bf16x8 b1 = *(const bf16x8*)&sB[(q0 + 16 + l16) * LK2 + kk + g * 8];
        acc00 = __builtin_amdgcn_mfma_f32_16x16x32_bf16(a0, b0, acc00, 0, 0, 0);
        acc01 = __builtin_amdgcn_mfma_f32_16x16x32_bf16(a0, b1, acc01, 0, 0, 0);
        acc10 = __builtin_amdgcn_mfma_f32_16x16x32_bf16(a1, b0, acc10, 0, 0, 0);
        acc11 = __builtin_amdgcn_mfma_f32_16x16x32_bf16(a1, b1, acc11, 0, 0, 0);
    }
    int colA = n0 + q0 + l16;
    int colB = colA + 16;
    float bA = bias1[colA], bB = bias1[colB];
#pragma unroll
    for (int r = 0; r < 4; ++r) {
        int rowi = g * 4 + r;
        int giA = i0 + m0 + rowi;
        int giB = giA + 16;
        if (giA < NN) {
            h1b[(size_t)giA * 256 + colA] = f2bf(fmaxf(acc00[r] + bA, 0.f));
            h1b[(size_t)giA * 256 + colB] = f2bf(fmaxf(acc01[r] + bB, 0.f));
        }
        if (giB < NN) {
            h1b[(size_t)giB * 256 + colA] = f2bf(fmaxf(acc10[r] + bA, 0.f));
            h1b[(size_t)giB * 256 + colB] = f2bf(fmaxf(acc11[r] + bB, 0.f));
        }
    }
}

// ------------------------------------------------------- layer-2 MFMA GEMM
// blockIdx.y==0: znb = bf16(h1@w2n), 48 cols packed in 24 dwords/row
// blockIdx.y==1: zsb = h1@w2s + bias2 -> fp32 (48 cols/row)
__global__ __launch_bounds__(256) void gemm2_mfma(
    const unsigned short* __restrict__ h1b, const unsigned short* __restrict__ WB2,
    const float* __restrict__ b2n, const float* __restrict__ b2s,
    unsigned* __restrict__ znb, float* __restrict__ zsb)
{
    __shared__ unsigned short sA[64 * LK2];
    __shared__ unsigned short sB[48 * LK2];
    const int tid = threadIdx.x;
    const int i0 = blockIdx.x * 64;
    const int n0 = blockIdx.y * 48;
    const int wv = tid >> 6, lane = tid & 63;
    const int g = lane >> 4, l16 = lane & 15;
    const int m0 = wv * 16;
    f32x4 acc[3] = {};

#pragma unroll
    for (int l = 0; l < 8; ++l) {
        int c = tid + l * 256;
        int r = c >> 5, c8 = (c & 31) * 8;
        int gi = i0 + r;
        int4 v = make_int4(0, 0, 0, 0);
        if (gi < NN) v = *(const int4*)&h1b[(size_t)gi * 256 + c8];
        *(int4*)&sA[r * LK2 + c8] = v;
    }
#pragma unroll
    for (int l = 0; l < 6; ++l) {
        int c = tid + l * 256;
        int r = c >> 5, c8 = (c & 31) * 8;
        *(int4*)&sB[r * LK2 + c8] = *(const int4*)&WB2[(size_t)(n0 + r) * 256 + c8];
    }
    __syncthreads();
#pragma unroll
    for (int kk = 0; kk < 256; kk += 32) {
        bf16x8 af = *(const bf16x8*)&sA[(m0 + l16) * LK2 + kk + g * 8];
#pragma unroll
        for (int ni = 0; ni < 3; ++ni) {
            bf16x8 bfv = *(const bf16x8*)&sB[(ni * 16 + l16) * LK2 + kk + g * 8];
            acc[ni] = __builtin_amdgcn_mfma_f32_16x16x32_bf16(af, bfv, acc[ni], 0, 0, 0);
        }
    }
    if (blockIdx.y == 0) {
#pragma unroll
        for (int ni = 0; ni < 3; ++ni) {
#pragma unroll
            for (int r = 0; r < 4; ++r) {
                int gi = i0 + m0 + g * 4 + r;
                float v = acc[ni][r];
                float vp = __shfl_down(v, 1);
                if (((l16 & 1) == 0) && gi < NN)
                    znb[(size_t)gi * 24 + ni * 8 + (l16 >> 1)] =
                        (unsigned)f2bf(v) | ((unsigned)f2bf(vp) << 16);
            }
        }
    } else {
#pragma unroll
        for (int ni = 0; ni < 3; ++ni) {
            int c = ni * 16 + l16;
            float bias = (c < CC) ? (b2n[c] + b2s[c]) : 0.f;
#pragma unroll
            for (int r = 0; r < 4; ++r) {
                int gi = i0 + m0 + g * 4 + r;
                if (gi < NN) zsb[(size_t)gi * 48 + c] = acc[ni][r] + bias;
            }
        }
    }
}

// --------------- masked-only loss: HALF-WAVE per node, 2 nodes per wave
// lanes 0-23 of each half own classes {2l, 2l+1}; 8-deep edge unroll.
__global__ __launch_bounds__(256) void loss_kernel(
    const unsigned* __restrict__ znb, const float* __restrict__ zsb,
    const int* __restrict__ rp, const int* __restrict__ csr,
    const float* __restrict__ inv,
    const int* __restrict__ y,
    const int* __restrict__ mcount, const int* __restrict__ mlist,
    float* __restrict__ accum)
{
    __shared__ float red[16];
    const int tid = threadIdx.x;
    const int wave = tid >> 6, lane = tid & 63;
    const int half = lane >> 5, hl = lane & 31;
    const int h32 = lane & 32;
    const bool act = hl < 24;
    const int dw = act ? hl : 0;
    const int W = gridDim.x * 8;          // nodes per stride: 4 waves x 2 halves
    const int M = mcount[0];
    float num = 0.f, den = 0.f;

    for (int p = (blockIdx.x * 4 + wave) * 2 + half; p < M; p += W) {
        int i = mlist[p];
        int s = rp[i], e = rp[i + 1];
        float plo[8] = {}, phi[8] = {};
        for (int base = s; base < e; base += 32) {
            int cnt = min(32, e - base);
            int myidx = csr[min(base + hl, e - 1)];
            int j = 0;
            for (; j + 8 <= cnt; j += 8) {
                unsigned uu[8];
#pragma unroll
                for (int k = 0; k < 8; ++k) {
                    int n = __shfl(myidx, h32 + j + k);
                    uu[k] = znb[(size_t)n * 24 + dw];
                }
#pragma unroll
                for (int k = 0; k < 8; ++k) {
                    plo[k] += bflo(uu[k]); phi[k] += bfhi(uu[k]);
                }
            }
            for (; j + 4 <= cnt; j += 4) {
                unsigned uu[4];
#pragma unroll
                for (int k = 0; k < 4; ++k) {
                    int n = __shfl(myidx, h32 + j + k);
                    uu[k] = znb[(size_t)n * 24 + dw];
                }
#pragma unroll
                for (int k = 0; k < 4; ++k) {
                    plo[k] += bflo(uu[k]); phi[k] += bfhi(uu[k]);
                }
            }
            for (; j < cnt; ++j) {
                int n = __shfl(myidx, h32 + j);
                unsigned u = znb[(size_t)n * 24 + dw];
                plo[0] += bflo(u); phi[0] += bfhi(u);
            }
        }
        float alo = ((plo[0] + plo[1]) + (plo[2] + plo[3])) +
                    ((plo[4] + plo[5]) + (plo[6] + plo[7]));
        float ahi = ((phi[0] + phi[1]) + (phi[2] + phi[3])) +
                    ((phi[4] + phi[5]) + (phi[6] + phi[7]));

        float sc = inv[i];
        float llo = -1e30f, lhi = -1e30f;
        if (act) {
            float2 zs = *(const float2*)&zsb[(size_t)i * 48 + 2 * hl];
            llo = alo * sc + zs.x;
            lhi = ahi * sc + zs.y;
        }
        if (hl == 23) lhi = -1e30f;      // class 47 invalid
        float mx = fmaxf(llo, lhi);
#pragma unroll
        for (int off = 16; off >= 1; off >>= 1)
            mx = fmaxf(mx, __shfl_xor(mx, off));
        float sm = act ? (__expf(llo - mx) + __expf(lhi - mx)) : 0.f;
#pragma unroll
        for (int off = 16; off >= 1; off >>= 1)
            sm += __shfl_xor(sm, off);
        float lse = mx + __logf(sm);
        int yi = y[i];
        float gl = __shfl(llo, h32 + (yi >> 1));
        float gh = __shfl(lhi, h32 + (yi >> 1));
        float ly = (yi & 1) ? gh : gl;
        if (hl == 0) { num += lse - ly; den += 1.f; }
    }
    if (hl == 0) {
        red[wave * 4 + half * 2]     = num;
        red[wave * 4 + half * 2 + 1] = den;
    }
    __syncthreads();
    if (tid == 0) {
        float n = 0.f, d = 0.f;
#pragma unroll
        for (int k = 0; k < 16; k += 2) { n += red[k]; d += red[k + 1]; }
        atomicAdd(&accum[0], n);
        atomicAdd(&accum[1], d);
    }
}

__global__ void finalize_kernel(const float* __restrict__ accum, float* __restrict__ out) {
    out[0] = accum[0] / fmaxf(accum[1], 1.0f);
}

// ---------------------------------------------------------------- launch
extern "C" void kernel_launch(void* const* d_in, const int* in_sizes, int n_in,
                              void* d_out, int out_size, void* d_ws, size_t ws_size,
                              hipStream_t stream) {
    const float* x   = (const float*)d_in[0];
    const int*   row = (const int*)d_in[1];
    const int*   col = (const int*)d_in[2];
    const int*   y   = (const int*)d_in[3];
    const int*   msk = (const int*)d_in[4];
    const float* w1n = (const float*)d_in[5];
    const float* b1n = (const float*)d_in[6];
    const float* w1s = (const float*)d_in[7];
    const float* b1s = (const float*)d_in[8];
    const float* w2n = (const float*)d_in[9];
    const float* b2n = (const float*)d_in[10];
    const float* w2s = (const float*)d_in[11];
    const float* b2s = (const float*)d_in[12];
    float* out = (float*)d_out;

    float* ws      = (float*)d_ws;
    float* accum   = ws;                                  // 64 f (mcount at +32)
    int*   mcount  = (int*)(ws + 32);
    int*   deg     = (int*)(ws + 64);                     // 50048
    int*   row_ptr = deg + 50048;                         // 50048
    int*   cursor  = row_ptr + 50048;                     // 50048
    int*   partial = cursor + 50048;                      // 256
    int*   csr     = partial + 256;                       // 800000
    float* inv     = (float*)(csr + 800000);              // 50048
    unsigned* xq   = (unsigned*)(inv + 50048);            // NN*32 (fp8 x)
    unsigned* ab   = xq + (size_t)NN * 32;                // NN*128 dwords ([a|x] bf16)
    unsigned short* h1b = (unsigned short*)(ab + (size_t)NN * 128);  // NN*256 bf16
    unsigned* znb  = (unsigned*)(h1b + (size_t)NN * 256); // NN*24 (48 bf16)
    float* zsb     = (float*)(znb + (size_t)NN * 24);     // NN*48 fp32
    unsigned short* WB1 = (unsigned short*)(zsb + (size_t)NN * 48);  // 256*256
    unsigned short* WB2 = WB1 + 65536;                    // 96*256
    float* bias1   = (float*)(WB2 + 24576);               // 256
    int*   mlist   = (int*)(bias1 + 256);                 // 50048

    const int NBLK = (NN + 255) / 256;    // 196

    (void)hipMemsetAsync(accum, 0, (64 + 50048) * sizeof(float), stream);  // accum+mcount+deg

    prep_kernel<<<(NN * 32 + 255) / 256, 256, 0, stream>>>(
        x, row, msk, w1n, w1s, b1n, b1s, w2n, w2s,
        deg, xq, ab, WB1, WB2, bias1, mcount, mlist);

    scan1<<<NBLK, 256, 0, stream>>>(deg, row_ptr, partial);
    scan2<<<1, 256, 0, stream>>>(partial, NBLK);
    scan3<<<NBLK, 256, 0, stream>>>(deg, row_ptr, partial, cursor, inv);
    fill_kernel<<<(EE + 255) / 256, 256, 0, stream>>>(row, col, cursor, csr);

    agg1<<<GS_BLOCKS, 256, 0, stream>>>(xq, row_ptr, csr, inv, ab);

    dim3 g1((NN + 63) / 64, 4);
    gemm1_mfma<<<g1, 256, 0, stream>>>((const unsigned short*)ab, WB1, bias1, h1b);

    dim3 g2((NN + 63) / 64, 2);
    gemm2_mfma<<<g2, 256, 0, stream>>>(h1b, WB2, b2n, b2s, znb, zsb);

    loss_kernel<<<GS_BLOCKS, 256, 0, stream>>>(
        znb, zsb, row_ptr, csr, inv, y, mcount, mlist, accum);

    finalize_kernel<<<1, 1, 0, stream>>>(accum, out);
}